// Round 4
// 1211.190 us; speedup vs baseline: 1.5126x; 1.5126x over previous
//
#include <hip/hip_runtime.h>
#include <hip/hip_bf16.h>

using bf16 = __hip_bfloat16;

constexpr int NB = 8, NS = 512, ND = 768, NH = 12, NE = 8, NF = 3072, NT = 4096;
constexpr int HG = 4;            // heads per attention group
constexpr int NG = NH / HG;      // 3 groups
constexpr int GW = HG * 64;      // 256: qkv group width
constexpr int FQ = 768;          // F columns per MoE pass
constexpr int NP = NF / FQ;      // 4 passes

typedef __attribute__((ext_vector_type(8))) short v8s;
typedef __attribute__((ext_vector_type(4))) float v4f;

__device__ __forceinline__ short f2bf(float v) {
    bf16 t = __float2bfloat16(v);
    return *reinterpret_cast<short*>(&t);
}
__device__ __forceinline__ float bf2f(short s) {
    bf16 t = *reinterpret_cast<bf16*>(&s);
    return __bfloat162float(t);
}

// ---------------- LayerNorm (fp32 in) -> TOUT out ----------------
template <typename TOUT>
__launch_bounds__(256)
__global__ void ln_kernel(const float* __restrict__ x, const float* __restrict__ g,
                          const float* __restrict__ b, TOUT* __restrict__ out) {
    const int t = blockIdx.x;
    const int tid = threadIdx.x;
    const float* xr = x + (size_t)t * ND;
    float v0 = xr[tid], v1 = xr[tid + 256], v2 = xr[tid + 512];
    float s = v0 + v1 + v2;
    float ss = v0 * v0 + v1 * v1 + v2 * v2;
#pragma unroll
    for (int off = 32; off >= 1; off >>= 1) {
        s += __shfl_xor(s, off);
        ss += __shfl_xor(ss, off);
    }
    __shared__ float rs[4], rss[4];
    const int wv = tid >> 6, ln = tid & 63;
    if (ln == 0) { rs[wv] = s; rss[wv] = ss; }
    __syncthreads();
    float S = rs[0] + rs[1] + rs[2] + rs[3];
    float SS = rss[0] + rss[1] + rss[2] + rss[3];
    float mu = S * (1.0f / ND);
    float var = SS * (1.0f / ND) - mu * mu;
    float r = rsqrtf(fmaxf(var, 0.f) + 1e-5f);
    TOUT* orow = out + (size_t)t * ND;
    float o0 = (v0 - mu) * r * g[tid]       + b[tid];
    float o1 = (v1 - mu) * r * g[tid + 256] + b[tid + 256];
    float o2 = (v2 - mu) * r * g[tid + 512] + b[tid + 512];
    if constexpr (sizeof(TOUT) == 2) {
        orow[tid] = __float2bfloat16(o0);
        orow[tid + 256] = __float2bfloat16(o1);
        orow[tid + 512] = __float2bfloat16(o2);
    } else {
        orow[tid] = o0; orow[tid + 256] = o1; orow[tid + 512] = o2;
    }
}

// ============ split-bf16 (bf16x3) MFMA GEMM core: fp32-accurate ============
// a = a_hi + a_lo (bf16 each); a*b ~= ah*bh + ah*bl + al*bh (rel err ~2^-18).
// 64x64 tile, BK=32, 4 waves, verified moe_gemm fragment layout:
//   A[m=lane&15][k=quad*8+j], B stored [n][k], D row=quad*4+reg, col=lane&15.
__device__ __forceinline__ void gemm3_core(const float* __restrict__ A, int lda,
                                           const float* __restrict__ Bsrc, int ldb,
                                           int Kd, int m0, v4f acc[4],
                                           short* Ah, short* Al, short* Bh, short* Bl) {
    const int tid = threadIdx.x, lane = tid & 63, wv = tid >> 6;
    const int qd = lane >> 4, l16 = lane & 15;
    const int ar = tid >> 2, ac = (tid & 3) * 8;   // A staging: row, k-offset
    const int bn = tid & 63, bk = (tid >> 6) * 8;  // B staging: n, k-offset
    const float* Arow = A + (size_t)(m0 + ar) * lda;
    for (int k0 = 0; k0 < Kd; k0 += 32) {
        {
            const float* asrc = Arow + k0 + ac;
            v8s ah, al;
#pragma unroll
            for (int j = 0; j < 8; j++) {
                float vv = asrc[j];
                short hi = f2bf(vv);
                ah[j] = hi;
                al[j] = f2bf(vv - bf2f(hi));
            }
            *(v8s*)&Ah[ar * 40 + ac] = ah;
            *(v8s*)&Al[ar * 40 + ac] = al;
        }
        {
            const float* bsrc = Bsrc + (size_t)(k0 + bk) * ldb + bn;
            v8s bh_, bl_;
#pragma unroll
            for (int j = 0; j < 8; j++) {
                float vv = bsrc[(size_t)j * ldb];
                short hi = f2bf(vv);
                bh_[j] = hi;
                bl_[j] = f2bf(vv - bf2f(hi));
            }
            *(v8s*)&Bh[bn * 40 + bk] = bh_;
            *(v8s*)&Bl[bn * 40 + bk] = bl_;
        }
        __syncthreads();
        v8s bhf = *(const v8s*)&Bh[(wv * 16 + l16) * 40 + qd * 8];
        v8s blf = *(const v8s*)&Bl[(wv * 16 + l16) * 40 + qd * 8];
#pragma unroll
        for (int t = 0; t < 4; t++) {
            v8s ahf = *(const v8s*)&Ah[(t * 16 + l16) * 40 + qd * 8];
            v8s alf = *(const v8s*)&Al[(t * 16 + l16) * 40 + qd * 8];
            acc[t] = __builtin_amdgcn_mfma_f32_16x16x32_bf16(ahf, bhf, acc[t], 0, 0, 0);
            acc[t] = __builtin_amdgcn_mfma_f32_16x16x32_bf16(ahf, blf, acc[t], 0, 0, 0);
            acc[t] = __builtin_amdgcn_mfma_f32_16x16x32_bf16(alf, bhf, acc[t], 0, 0, 0);
        }
        __syncthreads();
    }
}

// ---- generic split-bf16 GEMM. RES_MODE: 0 store, 1 store Res+acc, 2 C += acc ----
template <int RES_MODE>
__launch_bounds__(256)
__global__ void sgemm3(const float* __restrict__ A, int lda, const float* __restrict__ Bw,
                       int ldb, int bcol0, const float* __restrict__ Res,
                       float* __restrict__ C, int ldc, int Kd) {
    __shared__ short Ah[64 * 40], Al[64 * 40], Bh[64 * 40], Bl[64 * 40];
    const int m0 = blockIdx.x * 64, n0 = blockIdx.y * 64;
    v4f acc[4] = {};
    gemm3_core(A, lda, Bw + bcol0 + n0, ldb, Kd, m0, acc, Ah, Al, Bh, Bl);
    const int tid = threadIdx.x, lane = tid & 63, wv = tid >> 6;
    const int qd = lane >> 4, l16 = lane & 15;
    const int c = n0 + wv * 16 + l16;
#pragma unroll
    for (int t = 0; t < 4; t++)
#pragma unroll
        for (int rg = 0; rg < 4; rg++) {
            const int r = m0 + t * 16 + qd * 4 + rg;
            size_t ci = (size_t)r * ldc + c;
            if (RES_MODE == 0) C[ci] = acc[t][rg];
            else if (RES_MODE == 1) C[ci] = Res[ci] + acc[t][rg];
            else C[ci] += acc[t][rg];
        }
}

// ---- merged Q/K/V projection for one head-group (grid 64 x 12, 3 blocks/CU) ----
__launch_bounds__(256)
__global__ void qkv3(const float* __restrict__ h, const float* __restrict__ wq,
                     const float* __restrict__ wk, const float* __restrict__ wv,
                     int bcol0, float* __restrict__ qo, float* __restrict__ ko,
                     float* __restrict__ vo) {
    __shared__ short Ah[64 * 40], Al[64 * 40], Bh[64 * 40], Bl[64 * 40];
    const int m0 = blockIdx.x * 64;
    const int ysel = blockIdx.y >> 2, ny = blockIdx.y & 3;
    const int n0 = ny * 64;
    const float* Bw = (ysel == 0) ? wq : (ysel == 1) ? wk : wv;
    float* C = (ysel == 0) ? qo : (ysel == 1) ? ko : vo;
    v4f acc[4] = {};
    gemm3_core(h, ND, Bw + bcol0 + n0, ND, ND, m0, acc, Ah, Al, Bh, Bl);
    const int tid = threadIdx.x, lane = tid & 63, wv_ = tid >> 6;
    const int qd = lane >> 4, l16 = lane & 15;
    const int c = n0 + wv_ * 16 + l16;
#pragma unroll
    for (int t = 0; t < 4; t++)
#pragma unroll
        for (int rg = 0; rg < 4; rg++) {
            const int r = m0 + t * 16 + qd * 4 + rg;
            C[(size_t)r * GW + c] = acc[t][rg];
        }
}

// ------- fp32 flash attention (R0-verified logic; v4f-vectorized LDS traffic) -------
// q/k/v/o fp32 [NT, GW]; FMA order identical to the verified kernel.
__launch_bounds__(256)
__global__ void attn_kernel(const float* __restrict__ q, const float* __restrict__ k,
                            const float* __restrict__ v, float* __restrict__ o) {
    __shared__ float qs[64][68];
    __shared__ float kp[64][68]; // K tile, reused as P tile
    __shared__ float vs[64][68];
    const int qt = blockIdx.x, hl = blockIdx.y, b = blockIdx.z;
    const int tid = threadIdx.x, tx = tid & 15, ty = tid >> 4;
    const int hc = hl * 64;
    {
        const v4f* q4 = (const v4f*)(q + ((size_t)b * NS + qt * 64) * GW + hc);
#pragma unroll
        for (int i = 0; i < 4; i++) {
            int idx = tid + 256 * i;
            int r = idx >> 4, c4 = idx & 15;
            *(v4f*)&qs[r][c4 * 4] = q4[(size_t)r * (GW / 4) + c4];
        }
    }
    float oa[4][4] = {};
    float mi[4], li[4], al[4];
#pragma unroll
    for (int i = 0; i < 4; i++) { mi[i] = -1.0e30f; li[i] = 0.f; }
    for (int kt = 0; kt < NS / 64; kt++) {
        __syncthreads();
        {
            const v4f* k4 = (const v4f*)(k + ((size_t)b * NS + kt * 64) * GW + hc);
            const v4f* v4 = (const v4f*)(v + ((size_t)b * NS + kt * 64) * GW + hc);
#pragma unroll
            for (int i = 0; i < 4; i++) {
                int idx = tid + 256 * i;
                int r = idx >> 4, c4 = idx & 15;
                *(v4f*)&kp[r][c4 * 4] = k4[(size_t)r * (GW / 4) + c4];
                *(v4f*)&vs[r][c4 * 4] = v4[(size_t)r * (GW / 4) + c4];
            }
        }
        __syncthreads();
        float s[4][4] = {};
#pragma unroll
        for (int d0 = 0; d0 < 64; d0 += 4) {
            v4f av[4], bv[4];
#pragma unroll
            for (int i = 0; i < 4; i++) av[i] = *(const v4f*)&qs[ty + 16 * i][d0];
#pragma unroll
            for (int j = 0; j < 4; j++) bv[j] = *(const v4f*)&kp[tx + 16 * j][d0];
#pragma unroll
            for (int dd = 0; dd < 4; dd++)
#pragma unroll
                for (int i = 0; i < 4; i++)
#pragma unroll
                    for (int j = 0; j < 4; j++) s[i][j] += av[i][dd] * bv[j][dd];
        }
#pragma unroll
        for (int i = 0; i < 4; i++) {
#pragma unroll
            for (int j = 0; j < 4; j++) s[i][j] *= 0.125f; // 1/sqrt(DH=64)
            float mt = fmaxf(fmaxf(s[i][0], s[i][1]), fmaxf(s[i][2], s[i][3]));
#pragma unroll
            for (int off = 1; off < 16; off <<= 1) mt = fmaxf(mt, __shfl_xor(mt, off));
            float mn = fmaxf(mi[i], mt);
            al[i] = __expf(mi[i] - mn);
            mi[i] = mn;
            float rsum = 0.f;
#pragma unroll
            for (int j = 0; j < 4; j++) {
                s[i][j] = __expf(s[i][j] - mn);
                rsum += s[i][j];
            }
#pragma unroll
            for (int off = 1; off < 16; off <<= 1) rsum += __shfl_xor(rsum, off);
            li[i] = li[i] * al[i] + rsum;
        }
        __syncthreads(); // reads of kp-as-K done
#pragma unroll
        for (int i = 0; i < 4; i++)
#pragma unroll
            for (int j = 0; j < 4; j++) {
                kp[ty + 16 * i][tx + 16 * j] = s[i][j];
                oa[i][j] *= al[i];
            }
        __syncthreads(); // P visible
#pragma unroll
        for (int d0 = 0; d0 < 64; d0 += 4) {
            v4f av[4];
#pragma unroll
            for (int i = 0; i < 4; i++) av[i] = *(const v4f*)&kp[ty + 16 * i][d0];
#pragma unroll
            for (int dd = 0; dd < 4; dd++) {
                float bb[4];
#pragma unroll
                for (int j = 0; j < 4; j++) bb[j] = vs[d0 + dd][tx + 16 * j];
#pragma unroll
                for (int i = 0; i < 4; i++)
#pragma unroll
                    for (int j = 0; j < 4; j++) oa[i][j] += av[i][dd] * bb[j];
            }
        }
    }
#pragma unroll
    for (int i = 0; i < 4; i++) {
        float inv = 1.0f / li[i];
#pragma unroll
        for (int j = 0; j < 4; j++)
            o[((size_t)b * NS + qt * 64 + ty + 16 * i) * GW + hc + tx + 16 * j] = oa[i][j] * inv;
    }
}

// ------- Routing: inline fp32 LN2(x1) -> logits -> top-2. One wave per token. -------
__launch_bounds__(256)
__global__ void route_kernel(const float* __restrict__ x1, const float* __restrict__ lg,
                             const float* __restrict__ lb, const float* __restrict__ gw,
                             const float* __restrict__ gb, const float* __restrict__ be,
                             int* __restrict__ cnt, int* __restrict__ list,
                             float* __restrict__ gates) {
    const int lane = threadIdx.x & 63;
    const int t = blockIdx.x * 4 + (threadIdx.x >> 6);
    if (t >= NT) return;
    const float* xr = x1 + (size_t)t * ND;
    float xv[12];
    float s = 0.f, ss = 0.f;
#pragma unroll
    for (int i = 0; i < 12; i++) {
        xv[i] = xr[i * 64 + lane];
        s += xv[i];
        ss += xv[i] * xv[i];
    }
#pragma unroll
    for (int off = 32; off >= 1; off >>= 1) {
        s += __shfl_xor(s, off);
        ss += __shfl_xor(ss, off);
    }
    float mu = s * (1.0f / ND);
    float var = ss * (1.0f / ND) - mu * mu;
    float r = rsqrtf(fmaxf(var, 0.f) + 1e-5f);
    float le[NE];
#pragma unroll
    for (int e = 0; e < NE; e++) le[e] = 0.f;
#pragma unroll
    for (int i = 0; i < 12; i++) {
        int d = i * 64 + lane;
        float hn = (xv[i] - mu) * r * lg[d] + lb[d];
#pragma unroll
        for (int e = 0; e < NE; e++) le[e] += hn * gw[d * NE + e];
    }
#pragma unroll
    for (int off = 1; off < 64; off <<= 1)
#pragma unroll
        for (int e = 0; e < NE; e++) le[e] += __shfl_xor(le[e], off);
    float sel[NE];
#pragma unroll
    for (int e = 0; e < NE; e++) {
        le[e] += gb[e]; // TAU = 1
        sel[e] = le[e] + be[e];
    }
    int i1 = 0;
#pragma unroll
    for (int e = 1; e < NE; e++) if (sel[e] > sel[i1]) i1 = e;
    int i2 = (i1 == 0) ? 1 : 0;
#pragma unroll
    for (int e = 0; e < NE; e++) if (e != i1 && sel[e] > sel[i2]) i2 = e;
    float l1 = le[i1], l2 = le[i2];
    float m = fmaxf(l1, l2);
    float e1 = __expf(l1 - m), e2 = __expf(l2 - m);
    float inv = 1.0f / (e1 + e2);
    if (lane == 0) {
        gates[t * 2 + 0] = e1 * inv;
        gates[t * 2 + 1] = e2 * inv;
        int p1 = atomicAdd(&cnt[i1], 1);
        if (p1 < NT) list[i1 * NT + p1] = t * 2 + 0;
        int p2 = atomicAdd(&cnt[i2], 1);
        if (p2 < NT) list[i2 * NT + p2] = t * 2 + 1;
    }
}

// ==================== MFMA MoE GEMMs (verified, unchanged) ====================
__launch_bounds__(256)
__global__ void moe_gemm1(const bf16* __restrict__ h2, const float* __restrict__ w1,
                          const float* __restrict__ b1, const int* __restrict__ cnt,
                          const int* __restrict__ list, bf16* __restrict__ mid, int fcol0) {
    const int e = blockIdx.x >> 6, tile = blockIdx.x & 63;
    const int n = min(cnt[e], NT);
    const int r0 = tile * 64;
    if (r0 >= n) return;
    const int f0 = blockIdx.y * 64;
    __shared__ int ent[64];
    __shared__ short As[64 * 40];
    __shared__ short Bs[64 * 40];
    const int tid = threadIdx.x;
    const int lane = tid & 63, wv = tid >> 6;
    const int qd = lane >> 4, l16 = lane & 15;
    if (tid < 64) {
        int en = (r0 + tid < n) ? list[e * NT + r0 + tid] : -1;
        if (en < 0 || en >= 2 * NT) en = -1;
        ent[tid] = en;
    }
    __syncthreads();
    v4f acc[4] = {};
    const float* w1e = w1 + (size_t)e * ND * NF + fcol0 + f0;
    const int ar = tid >> 2, ac = (tid & 3) * 8;
    const int bn = tid & 63, bk = (tid >> 6) * 8;
    const int aen = ent[ar];
    for (int k0 = 0; k0 < ND; k0 += 32) {
        v8s av = {};
        if (aen >= 0)
            av = *(const v8s*)((const short*)h2 + (size_t)(aen >> 1) * ND + k0 + ac);
        *(v8s*)&As[ar * 40 + ac] = av;
        {
            const float* src = w1e + (size_t)(k0 + bk) * NF + bn;
            v8s bv;
#pragma unroll
            for (int j = 0; j < 8; j++) bv[j] = f2bf(src[(size_t)j * NF]);
            *(v8s*)&Bs[bn * 40 + bk] = bv;
        }
        __syncthreads();
        v8s bfrag = *(const v8s*)&Bs[(wv * 16 + l16) * 40 + qd * 8];
#pragma unroll
        for (int t = 0; t < 4; t++) {
            v8s afrag = *(const v8s*)&As[(t * 16 + l16) * 40 + qd * 8];
            acc[t] = __builtin_amdgcn_mfma_f32_16x16x32_bf16(afrag, bfrag, acc[t], 0, 0, 0);
        }
        __syncthreads();
    }
    const int col = wv * 16 + l16;
    const float bias = b1[e * NF + fcol0 + f0 + col];
#pragma unroll
    for (int t = 0; t < 4; t++) {
#pragma unroll
        for (int rg = 0; rg < 4; rg++) {
            int en = ent[t * 16 + qd * 4 + rg];
            if (en < 0) continue;
            float xv = acc[t][rg] + bias;
            float th = tanhf(0.7978845608028654f * (xv + 0.044715f * xv * xv * xv));
            mid[((size_t)((en & 1) * NT) + (en >> 1)) * FQ + f0 + col] =
                __float2bfloat16(0.5f * xv * (1.0f + th));
        }
    }
}

__launch_bounds__(256)
__global__ void moe_gemm2(const bf16* __restrict__ mid, const float* __restrict__ w2,
                          const float* __restrict__ b2, const int* __restrict__ cnt,
                          const int* __restrict__ list, const float* __restrict__ gates,
                          float* __restrict__ x1, int fcol0, int add_b2) {
    const int e = blockIdx.x >> 6, tile = blockIdx.x & 63;
    const int n = min(cnt[e], NT);
    const int r0 = tile * 64;
    if (r0 >= n) return;
    const int d0 = blockIdx.y * 64;
    __shared__ int ent[64];
    __shared__ short As[64 * 40];
    __shared__ short Bs[64 * 40];
    const int tid = threadIdx.x;
    const int lane = tid & 63, wv = tid >> 6;
    const int qd = lane >> 4, l16 = lane & 15;
    if (tid < 64) {
        int en = (r0 + tid < n) ? list[e * NT + r0 + tid] : -1;
        if (en < 0 || en >= 2 * NT) en = -1;
        ent[tid] = en;
    }
    __syncthreads();
    v4f acc[4] = {};
    const float* w2e = w2 + (size_t)e * NF * ND + d0;
    const int ar = tid >> 2, ac = (tid & 3) * 8;
    const int bn = tid & 63, bk = (tid >> 6) * 8;
    const int aen = ent[ar];
    for (int k0 = 0; k0 < FQ; k0 += 32) {
        v8s av = {};
        if (aen >= 0)
            av = *(const v8s*)((const short*)mid +
                               ((size_t)((aen & 1) * NT) + (aen >> 1)) * FQ + k0 + ac);
        *(v8s*)&As[ar * 40 + ac] = av;
        {
            const float* src = w2e + (size_t)(fcol0 + k0 + bk) * ND + bn;
            v8s bv;
#pragma unroll
            for (int j = 0; j < 8; j++) bv[j] = f2bf(src[(size_t)j * ND]);
            *(v8s*)&Bs[bn * 40 + bk] = bv;
        }
        __syncthreads();
        v8s bfrag = *(const v8s*)&Bs[(wv * 16 + l16) * 40 + qd * 8];
#pragma unroll
        for (int t = 0; t < 4; t++) {
            v8s afrag = *(const v8s*)&As[(t * 16 + l16) * 40 + qd * 8];
            acc[t] = __builtin_amdgcn_mfma_f32_16x16x32_bf16(afrag, bfrag, acc[t], 0, 0, 0);
        }
        __syncthreads();
    }
    const int col = wv * 16 + l16;
    const float bias = add_b2 ? b2[e * ND + d0 + col] : 0.f;
#pragma unroll
    for (int t = 0; t < 4; t++) {
#pragma unroll
        for (int rg = 0; rg < 4; rg++) {
            int en = ent[t * 16 + qd * 4 + rg];
            if (en < 0) continue;
            float g = gates[en];
            atomicAdd(&x1[(size_t)(en >> 1) * ND + d0 + col], g * (acc[t][rg] + bias));
        }
    }
}

// ---------------- Final: out = x1 (fp32 copy) ----------------
__launch_bounds__(256)
__global__ void final_kernel(const float* __restrict__ x1, float* __restrict__ out) {
    int i = blockIdx.x * 256 + threadIdx.x;
    out[i] = x1[i];
}

extern "C" void kernel_launch(void* const* d_in, const int* in_sizes, int n_in,
                              void* d_out, int out_size, void* d_ws, size_t ws_size,
                              hipStream_t stream) {
    const float* x    = (const float*)d_in[0];
    const float* wq   = (const float*)d_in[1];
    const float* wk   = (const float*)d_in[2];
    const float* wvp  = (const float*)d_in[3];
    const float* wo   = (const float*)d_in[4];
    const float* ln1g = (const float*)d_in[5];
    const float* ln1b = (const float*)d_in[6];
    const float* ln2g = (const float*)d_in[7];
    const float* ln2b = (const float*)d_in[8];
    const float* gw   = (const float*)d_in[9];
    const float* gb   = (const float*)d_in[10];
    const float* be   = (const float*)d_in[11];
    const float* w1   = (const float*)d_in[12];
    const float* b1   = (const float*)d_in[13];
    const float* w2   = (const float*)d_in[14];
    const float* b2   = (const float*)d_in[15];
    float* out = (float*)d_out;

    const size_t TDn = (size_t)NT * ND; // 3,145,728
    const size_t TGn = (size_t)NT * GW; // 1,048,576
    float* W = (float*)d_ws;
    // Workspace 40.2 MiB (identical to the verified R0 layout):
    // [routing 41216 f][x1 fp32 TDn][h fp32 TDn][R: q,k,v,og fp32 4*TGn]
    // h2 (bf16, TDn) reuses h's region; mid (bf16, 2*NT*FQ = 2*TDn) reuses R.
    int*   cnt   = (int*)W;                  // 8
    int*   list  = cnt + NE;                 // 32768
    float* gates = (float*)(list + NE * NT); // 8192 (ends 40968)
    float* x1 = W + 41216;
    float* h  = x1 + TDn;
    float* R0 = h + TDn;
    float* q  = R0;
    float* k  = R0 + TGn;
    float* v  = R0 + 2 * TGn;
    float* og = R0 + 3 * TGn;
    bf16*  h2  = (bf16*)h;   // LN2 out (bf16), overwrites LN1 h after attention
    bf16*  mid = (bf16*)R0;  // [2*NT][FQ] bf16 = 2*TDn bf16, fits in 4*TGn floats

    hipMemsetAsync(cnt, 0, NE * sizeof(int), stream);

    ln_kernel<float><<<NT, 256, 0, stream>>>(x, ln1g, ln1b, h);
    for (int g = 0; g < NG; g++) {
        qkv3<<<dim3(NT / 64, 12), 256, 0, stream>>>(h, wq, wk, wvp, g * GW, q, k, v);
        attn_kernel<<<dim3(NS / 64, HG, NB), 256, 0, stream>>>(q, k, v, og);
        // x1 (g==0: = x + og@wo_g ; else += og@wo_g). wo rows g*GW..(g+1)*GW.
        if (g == 0)
            sgemm3<1><<<dim3(NT / 64, ND / 64), 256, 0, stream>>>(
                og, GW, wo + (size_t)g * GW * ND, ND, 0, x, x1, ND, GW);
        else
            sgemm3<2><<<dim3(NT / 64, ND / 64), 256, 0, stream>>>(
                og, GW, wo + (size_t)g * GW * ND, ND, 0, nullptr, x1, ND, GW);
    }
    route_kernel<<<NT / 4, 256, 0, stream>>>(x1, ln2g, ln2b, gw, gb, be, cnt, list, gates);
    ln_kernel<bf16><<<NT, 256, 0, stream>>>(x1, ln2g, ln2b, h2);
    for (int p = 0; p < NP; p++) {
        int fcol0 = p * FQ;
        moe_gemm1<<<dim3(NE * (NT / 64), FQ / 64), 256, 0, stream>>>(
            h2, w1, b1, cnt, list, mid, fcol0);
        moe_gemm2<<<dim3(NE * (NT / 64), ND / 64), 256, 0, stream>>>(
            mid, w2, b2, cnt, list, gates, x1, fcol0, p == 0 ? 1 : 0);
    }
    final_kernel<<<TDn / 256, 256, 0, stream>>>(x1, out);
}

// Round 5
// 1197.553 us; speedup vs baseline: 1.5298x; 1.0114x over previous
//
#include <hip/hip_runtime.h>
#include <hip/hip_bf16.h>

using bf16 = __hip_bfloat16;

constexpr int NB = 8, NS = 512, ND = 768, NH = 12, NE = 8, NF = 3072, NT = 4096;
constexpr int HG = 4;            // heads per attention group
constexpr int NG = NH / HG;      // 3 groups
constexpr int GW = HG * 64;      // 256: qkv group width
constexpr int FQ = 768;          // F columns per MoE pass
constexpr int NP = NF / FQ;      // 4 passes

typedef __attribute__((ext_vector_type(8))) short v8s;
typedef __attribute__((ext_vector_type(4))) float v4f;

__device__ __forceinline__ short f2bf(float v) {
    bf16 t = __float2bfloat16(v);
    return *reinterpret_cast<short*>(&t);
}
__device__ __forceinline__ float bf2f(short s) {
    bf16 t = *reinterpret_cast<bf16*>(&s);
    return __bfloat162float(t);
}

// ---------------- LayerNorm (fp32 in) -> fp32 out (LN1 only) ----------------
__launch_bounds__(256)
__global__ void ln_kernel(const float* __restrict__ x, const float* __restrict__ g,
                          const float* __restrict__ b, float* __restrict__ out) {
    const int t = blockIdx.x;
    const int tid = threadIdx.x;
    const float* xr = x + (size_t)t * ND;
    float v0 = xr[tid], v1 = xr[tid + 256], v2 = xr[tid + 512];
    float s = v0 + v1 + v2;
    float ss = v0 * v0 + v1 * v1 + v2 * v2;
#pragma unroll
    for (int off = 32; off >= 1; off >>= 1) {
        s += __shfl_xor(s, off);
        ss += __shfl_xor(ss, off);
    }
    __shared__ float rs[4], rss[4];
    const int wv = tid >> 6, ln = tid & 63;
    if (ln == 0) { rs[wv] = s; rss[wv] = ss; }
    __syncthreads();
    float S = rs[0] + rs[1] + rs[2] + rs[3];
    float SS = rss[0] + rss[1] + rss[2] + rss[3];
    float mu = S * (1.0f / ND);
    float var = SS * (1.0f / ND) - mu * mu;
    float r = rsqrtf(fmaxf(var, 0.f) + 1e-5f);
    float* orow = out + (size_t)t * ND;
    orow[tid]       = (v0 - mu) * r * g[tid]       + b[tid];
    orow[tid + 256] = (v1 - mu) * r * g[tid + 256] + b[tid + 256];
    orow[tid + 512] = (v2 - mu) * r * g[tid + 512] + b[tid + 512];
}

// ============ split-bf16 (bf16x3) MFMA GEMM core: fp32-accurate ============
// a = a_hi + a_lo (bf16 each); a*b ~= ah*bh + ah*bl + al*bh (rel err ~2^-18).
// 64x64 tile, BK=32, 4 waves, verified moe_gemm fragment layout:
//   A[m=lane&15][k=quad*8+j], B stored [n][k], D row=quad*4+reg, col=lane&15.
__device__ __forceinline__ void gemm3_core(const float* __restrict__ A, int lda,
                                           const float* __restrict__ Bsrc, int ldb,
                                           int Kd, int m0, v4f acc[4],
                                           short* Ah, short* Al, short* Bh, short* Bl) {
    const int tid = threadIdx.x, lane = tid & 63, wv = tid >> 6;
    const int qd = lane >> 4, l16 = lane & 15;
    const int ar = tid >> 2, ac = (tid & 3) * 8;   // A staging: row, k-offset
    const int bn = tid & 63, bk = (tid >> 6) * 8;  // B staging: n, k-offset
    const float* Arow = A + (size_t)(m0 + ar) * lda;
    for (int k0 = 0; k0 < Kd; k0 += 32) {
        {
            const float* asrc = Arow + k0 + ac;
            v8s ah, al;
#pragma unroll
            for (int j = 0; j < 8; j++) {
                float vv = asrc[j];
                short hi = f2bf(vv);
                ah[j] = hi;
                al[j] = f2bf(vv - bf2f(hi));
            }
            *(v8s*)&Ah[ar * 40 + ac] = ah;
            *(v8s*)&Al[ar * 40 + ac] = al;
        }
        {
            const float* bsrc = Bsrc + (size_t)(k0 + bk) * ldb + bn;
            v8s bh_, bl_;
#pragma unroll
            for (int j = 0; j < 8; j++) {
                float vv = bsrc[(size_t)j * ldb];
                short hi = f2bf(vv);
                bh_[j] = hi;
                bl_[j] = f2bf(vv - bf2f(hi));
            }
            *(v8s*)&Bh[bn * 40 + bk] = bh_;
            *(v8s*)&Bl[bn * 40 + bk] = bl_;
        }
        __syncthreads();
        v8s bhf = *(const v8s*)&Bh[(wv * 16 + l16) * 40 + qd * 8];
        v8s blf = *(const v8s*)&Bl[(wv * 16 + l16) * 40 + qd * 8];
#pragma unroll
        for (int t = 0; t < 4; t++) {
            v8s ahf = *(const v8s*)&Ah[(t * 16 + l16) * 40 + qd * 8];
            v8s alf = *(const v8s*)&Al[(t * 16 + l16) * 40 + qd * 8];
            acc[t] = __builtin_amdgcn_mfma_f32_16x16x32_bf16(ahf, bhf, acc[t], 0, 0, 0);
            acc[t] = __builtin_amdgcn_mfma_f32_16x16x32_bf16(ahf, blf, acc[t], 0, 0, 0);
            acc[t] = __builtin_amdgcn_mfma_f32_16x16x32_bf16(alf, bhf, acc[t], 0, 0, 0);
        }
        __syncthreads();
    }
}

// ---- generic split-bf16 GEMM. RES_MODE: 0 store, 1 store Res+acc, 2 C += acc ----
template <int RES_MODE>
__launch_bounds__(256)
__global__ void sgemm3(const float* __restrict__ A, int lda, const float* __restrict__ Bw,
                       int ldb, int bcol0, const float* __restrict__ Res,
                       float* __restrict__ C, int ldc, int Kd) {
    __shared__ short Ah[64 * 40], Al[64 * 40], Bh[64 * 40], Bl[64 * 40];
    const int m0 = blockIdx.x * 64, n0 = blockIdx.y * 64;
    v4f acc[4] = {};
    gemm3_core(A, lda, Bw + bcol0 + n0, ldb, Kd, m0, acc, Ah, Al, Bh, Bl);
    const int tid = threadIdx.x, lane = tid & 63, wv = tid >> 6;
    const int qd = lane >> 4, l16 = lane & 15;
    const int c = n0 + wv * 16 + l16;
#pragma unroll
    for (int t = 0; t < 4; t++)
#pragma unroll
        for (int rg = 0; rg < 4; rg++) {
            const int r = m0 + t * 16 + qd * 4 + rg;
            size_t ci = (size_t)r * ldc + c;
            if (RES_MODE == 0) C[ci] = acc[t][rg];
            else if (RES_MODE == 1) C[ci] = Res[ci] + acc[t][rg];
            else C[ci] += acc[t][rg];
        }
}

// ---- merged Q/K/V projection for one head-group (grid 64 x 12, 3 blocks/CU) ----
__launch_bounds__(256)
__global__ void qkv3(const float* __restrict__ h, const float* __restrict__ wq,
                     const float* __restrict__ wk, const float* __restrict__ wv,
                     int bcol0, float* __restrict__ qo, float* __restrict__ ko,
                     float* __restrict__ vo) {
    __shared__ short Ah[64 * 40], Al[64 * 40], Bh[64 * 40], Bl[64 * 40];
    const int m0 = blockIdx.x * 64;
    const int ysel = blockIdx.y >> 2, ny = blockIdx.y & 3;
    const int n0 = ny * 64;
    const float* Bw = (ysel == 0) ? wq : (ysel == 1) ? wk : wv;
    float* C = (ysel == 0) ? qo : (ysel == 1) ? ko : vo;
    v4f acc[4] = {};
    gemm3_core(h, ND, Bw + bcol0 + n0, ND, ND, m0, acc, Ah, Al, Bh, Bl);
    const int tid = threadIdx.x, lane = tid & 63, wv_ = tid >> 6;
    const int qd = lane >> 4, l16 = lane & 15;
    const int c = n0 + wv_ * 16 + l16;
#pragma unroll
    for (int t = 0; t < 4; t++)
#pragma unroll
        for (int rg = 0; rg < 4; rg++) {
            const int r = m0 + t * 16 + qd * 4 + rg;
            C[(size_t)r * GW + c] = acc[t][rg];
        }
}

// ------- fp32 flash attention: 512 threads / 8 waves, 2 q-subtiles of 32 rows -------
// Per-element FMA order is bit-identical to the verified 256-thread version;
// only the thread->work mapping changed (2x waves/CU for latency hiding).
__launch_bounds__(512)
__global__ void attn_kernel(const float* __restrict__ q, const float* __restrict__ k,
                            const float* __restrict__ v, float* __restrict__ o) {
    __shared__ float qs[64][68];
    __shared__ float kp[64][68]; // K tile, reused as P tile (64 rows = both halves)
    __shared__ float vs[64][68];
    const int qt = blockIdx.x, hl = blockIdx.y, b = blockIdx.z;
    const int tid = threadIdx.x;
    const int half = tid >> 8, t8 = tid & 255;
    const int tx = t8 & 15, ty = t8 >> 4;   // ty 0..15
    const int hc = hl * 64;
    const int rb = half * 32 + ty;          // own rows rb + 16*i, i<2
    {
        const v4f* q4 = (const v4f*)(q + ((size_t)b * NS + qt * 64) * GW + hc);
#pragma unroll
        for (int i = 0; i < 2; i++) {
            int idx = tid + 512 * i;
            int r = idx >> 4, c4 = idx & 15;
            *(v4f*)&qs[r][c4 * 4] = q4[(size_t)r * (GW / 4) + c4];
        }
    }
    float oa[2][4] = {};
    float mi[2], li[2], al[2];
#pragma unroll
    for (int i = 0; i < 2; i++) { mi[i] = -1.0e30f; li[i] = 0.f; }
    for (int kt = 0; kt < NS / 64; kt++) {
        __syncthreads();
        {
            const v4f* k4 = (const v4f*)(k + ((size_t)b * NS + kt * 64) * GW + hc);
            const v4f* v4 = (const v4f*)(v + ((size_t)b * NS + kt * 64) * GW + hc);
#pragma unroll
            for (int i = 0; i < 2; i++) {
                int idx = tid + 512 * i;
                int r = idx >> 4, c4 = idx & 15;
                *(v4f*)&kp[r][c4 * 4] = k4[(size_t)r * (GW / 4) + c4];
                *(v4f*)&vs[r][c4 * 4] = v4[(size_t)r * (GW / 4) + c4];
            }
        }
        __syncthreads();
        float s[2][4] = {};
#pragma unroll
        for (int d0 = 0; d0 < 64; d0 += 4) {
            v4f av[2], bv[4];
#pragma unroll
            for (int i = 0; i < 2; i++) av[i] = *(const v4f*)&qs[rb + 16 * i][d0];
#pragma unroll
            for (int j = 0; j < 4; j++) bv[j] = *(const v4f*)&kp[tx + 16 * j][d0];
#pragma unroll
            for (int dd = 0; dd < 4; dd++)
#pragma unroll
                for (int i = 0; i < 2; i++)
#pragma unroll
                    for (int j = 0; j < 4; j++) s[i][j] += av[i][dd] * bv[j][dd];
        }
#pragma unroll
        for (int i = 0; i < 2; i++) {
#pragma unroll
            for (int j = 0; j < 4; j++) s[i][j] *= 0.125f; // 1/sqrt(DH=64)
            float mt = fmaxf(fmaxf(s[i][0], s[i][1]), fmaxf(s[i][2], s[i][3]));
#pragma unroll
            for (int off = 1; off < 16; off <<= 1) mt = fmaxf(mt, __shfl_xor(mt, off));
            float mn = fmaxf(mi[i], mt);
            al[i] = __expf(mi[i] - mn);
            mi[i] = mn;
            float rsum = 0.f;
#pragma unroll
            for (int j = 0; j < 4; j++) {
                s[i][j] = __expf(s[i][j] - mn);
                rsum += s[i][j];
            }
#pragma unroll
            for (int off = 1; off < 16; off <<= 1) rsum += __shfl_xor(rsum, off);
            li[i] = li[i] * al[i] + rsum;
        }
        __syncthreads(); // reads of kp-as-K done
#pragma unroll
        for (int i = 0; i < 2; i++)
#pragma unroll
            for (int j = 0; j < 4; j++) {
                kp[rb + 16 * i][tx + 16 * j] = s[i][j];
                oa[i][j] *= al[i];
            }
        __syncthreads(); // P visible
#pragma unroll
        for (int d0 = 0; d0 < 64; d0 += 4) {
            v4f av[2];
#pragma unroll
            for (int i = 0; i < 2; i++) av[i] = *(const v4f*)&kp[rb + 16 * i][d0];
#pragma unroll
            for (int dd = 0; dd < 4; dd++) {
                float bb[4];
#pragma unroll
                for (int j = 0; j < 4; j++) bb[j] = vs[d0 + dd][tx + 16 * j];
#pragma unroll
                for (int i = 0; i < 2; i++)
#pragma unroll
                    for (int j = 0; j < 4; j++) oa[i][j] += av[i][dd] * bb[j];
            }
        }
    }
#pragma unroll
    for (int i = 0; i < 2; i++) {
        float inv = 1.0f / li[i];
#pragma unroll
        for (int j = 0; j < 4; j++)
            o[((size_t)b * NS + qt * 64 + rb + 16 * i) * GW + hc + tx + 16 * j] = oa[i][j] * inv;
    }
}

// ------- Routing + fused LN2: x1 -> (h2 bf16, top-2 lists, gates) -------
// Top-2 selection is register-only (no runtime array indexing -> no scratch).
__launch_bounds__(256)
__global__ void route_kernel(const float* __restrict__ x1, const float* __restrict__ lg,
                             const float* __restrict__ lb, const float* __restrict__ gw,
                             const float* __restrict__ gb, const float* __restrict__ be,
                             int* __restrict__ cnt, int* __restrict__ list,
                             float* __restrict__ gates, bf16* __restrict__ h2) {
    const int lane = threadIdx.x & 63;
    const int t = blockIdx.x * 4 + (threadIdx.x >> 6);
    if (t >= NT) return;
    const float* xr = x1 + (size_t)t * ND;
    float xv[12];
    float s = 0.f, ss = 0.f;
#pragma unroll
    for (int i = 0; i < 12; i++) {
        xv[i] = xr[i * 64 + lane];
        s += xv[i];
        ss += xv[i] * xv[i];
    }
#pragma unroll
    for (int off = 32; off >= 1; off >>= 1) {
        s += __shfl_xor(s, off);
        ss += __shfl_xor(ss, off);
    }
    float mu = s * (1.0f / ND);
    float var = ss * (1.0f / ND) - mu * mu;
    float r = rsqrtf(fmaxf(var, 0.f) + 1e-5f);
    float le[NE];
#pragma unroll
    for (int e = 0; e < NE; e++) le[e] = 0.f;
    bf16* h2r = h2 + (size_t)t * ND;
#pragma unroll
    for (int i = 0; i < 12; i++) {
        int d = i * 64 + lane;
        float hn = (xv[i] - mu) * r * lg[d] + lb[d];
        h2r[d] = __float2bfloat16(hn);   // fused LN2 output
#pragma unroll
        for (int e = 0; e < NE; e++) le[e] += hn * gw[d * NE + e];
    }
#pragma unroll
    for (int off = 1; off < 64; off <<= 1)
#pragma unroll
        for (int e = 0; e < NE; e++) le[e] += __shfl_xor(le[e], off);
    // register-only top-2 over sel = le + gb + be (gates use le + gb only)
    float m1 = -1.0e30f, m2 = -1.0e30f, l1 = 0.f, l2 = 0.f;
    int i1 = 0, i2 = 0;
#pragma unroll
    for (int e = 0; e < NE; e++) {
        float lv = le[e] + gb[e];   // TAU = 1
        float sv = lv + be[e];
        bool g1 = sv > m1;
        float pm1 = m1, pl1 = l1; int pi1 = i1;
        m1 = g1 ? sv : m1; l1 = g1 ? lv : l1; i1 = g1 ? e : i1;
        bool g2 = (!g1) && (sv > m2);
        m2 = g1 ? pm1 : (g2 ? sv : m2);
        l2 = g1 ? pl1 : (g2 ? lv : l2);
        i2 = g1 ? pi1 : (g2 ? e : i2);
    }
    float m = fmaxf(l1, l2);
    float e1 = __expf(l1 - m), e2 = __expf(l2 - m);
    float inv = 1.0f / (e1 + e2);
    if (lane == 0) {
        gates[t * 2 + 0] = e1 * inv;
        gates[t * 2 + 1] = e2 * inv;
        int p1 = atomicAdd(&cnt[i1], 1);
        if (p1 < NT) list[i1 * NT + p1] = t * 2 + 0;
        int p2 = atomicAdd(&cnt[i2], 1);
        if (p2 < NT) list[i2 * NT + p2] = t * 2 + 1;
    }
}

// ==================== MFMA MoE GEMMs (verified, unchanged) ====================
__launch_bounds__(256)
__global__ void moe_gemm1(const bf16* __restrict__ h2, const float* __restrict__ w1,
                          const float* __restrict__ b1, const int* __restrict__ cnt,
                          const int* __restrict__ list, bf16* __restrict__ mid, int fcol0) {
    const int e = blockIdx.x >> 6, tile = blockIdx.x & 63;
    const int n = min(cnt[e], NT);
    const int r0 = tile * 64;
    if (r0 >= n) return;
    const int f0 = blockIdx.y * 64;
    __shared__ int ent[64];
    __shared__ short As[64 * 40];
    __shared__ short Bs[64 * 40];
    const int tid = threadIdx.x;
    const int lane = tid & 63, wv = tid >> 6;
    const int qd = lane >> 4, l16 = lane & 15;
    if (tid < 64) {
        int en = (r0 + tid < n) ? list[e * NT + r0 + tid] : -1;
        if (en < 0 || en >= 2 * NT) en = -1;
        ent[tid] = en;
    }
    __syncthreads();
    v4f acc[4] = {};
    const float* w1e = w1 + (size_t)e * ND * NF + fcol0 + f0;
    const int ar = tid >> 2, ac = (tid & 3) * 8;
    const int bn = tid & 63, bk = (tid >> 6) * 8;
    const int aen = ent[ar];
    for (int k0 = 0; k0 < ND; k0 += 32) {
        v8s av = {};
        if (aen >= 0)
            av = *(const v8s*)((const short*)h2 + (size_t)(aen >> 1) * ND + k0 + ac);
        *(v8s*)&As[ar * 40 + ac] = av;
        {
            const float* src = w1e + (size_t)(k0 + bk) * NF + bn;
            v8s bv;
#pragma unroll
            for (int j = 0; j < 8; j++) bv[j] = f2bf(src[(size_t)j * NF]);
            *(v8s*)&Bs[bn * 40 + bk] = bv;
        }
        __syncthreads();
        v8s bfrag = *(const v8s*)&Bs[(wv * 16 + l16) * 40 + qd * 8];
#pragma unroll
        for (int t = 0; t < 4; t++) {
            v8s afrag = *(const v8s*)&As[(t * 16 + l16) * 40 + qd * 8];
            acc[t] = __builtin_amdgcn_mfma_f32_16x16x32_bf16(afrag, bfrag, acc[t], 0, 0, 0);
        }
        __syncthreads();
    }
    const int col = wv * 16 + l16;
    const float bias = b1[e * NF + fcol0 + f0 + col];
#pragma unroll
    for (int t = 0; t < 4; t++) {
#pragma unroll
        for (int rg = 0; rg < 4; rg++) {
            int en = ent[t * 16 + qd * 4 + rg];
            if (en < 0) continue;
            float xv = acc[t][rg] + bias;
            float th = tanhf(0.7978845608028654f * (xv + 0.044715f * xv * xv * xv));
            mid[((size_t)((en & 1) * NT) + (en >> 1)) * FQ + f0 + col] =
                __float2bfloat16(0.5f * xv * (1.0f + th));
        }
    }
}

__launch_bounds__(256)
__global__ void moe_gemm2(const bf16* __restrict__ mid, const float* __restrict__ w2,
                          const float* __restrict__ b2, const int* __restrict__ cnt,
                          const int* __restrict__ list, const float* __restrict__ gates,
                          float* __restrict__ x1, int fcol0, int add_b2) {
    const int e = blockIdx.x >> 6, tile = blockIdx.x & 63;
    const int n = min(cnt[e], NT);
    const int r0 = tile * 64;
    if (r0 >= n) return;
    const int d0 = blockIdx.y * 64;
    __shared__ int ent[64];
    __shared__ short As[64 * 40];
    __shared__ short Bs[64 * 40];
    const int tid = threadIdx.x;
    const int lane = tid & 63, wv = tid >> 6;
    const int qd = lane >> 4, l16 = lane & 15;
    if (tid < 64) {
        int en = (r0 + tid < n) ? list[e * NT + r0 + tid] : -1;
        if (en < 0 || en >= 2 * NT) en = -1;
        ent[tid] = en;
    }
    __syncthreads();
    v4f acc[4] = {};
    const float* w2e = w2 + (size_t)e * NF * ND + d0;
    const int ar = tid >> 2, ac = (tid & 3) * 8;
    const int bn = tid & 63, bk = (tid >> 6) * 8;
    const int aen = ent[ar];
    for (int k0 = 0; k0 < FQ; k0 += 32) {
        v8s av = {};
        if (aen >= 0)
            av = *(const v8s*)((const short*)mid +
                               ((size_t)((aen & 1) * NT) + (aen >> 1)) * FQ + k0 + ac);
        *(v8s*)&As[ar * 40 + ac] = av;
        {
            const float* src = w2e + (size_t)(fcol0 + k0 + bk) * ND + bn;
            v8s bv;
#pragma unroll
            for (int j = 0; j < 8; j++) bv[j] = f2bf(src[(size_t)j * ND]);
            *(v8s*)&Bs[bn * 40 + bk] = bv;
        }
        __syncthreads();
        v8s bfrag = *(const v8s*)&Bs[(wv * 16 + l16) * 40 + qd * 8];
#pragma unroll
        for (int t = 0; t < 4; t++) {
            v8s afrag = *(const v8s*)&As[(t * 16 + l16) * 40 + qd * 8];
            acc[t] = __builtin_amdgcn_mfma_f32_16x16x32_bf16(afrag, bfrag, acc[t], 0, 0, 0);
        }
        __syncthreads();
    }
    const int col = wv * 16 + l16;
    const float bias = add_b2 ? b2[e * ND + d0 + col] : 0.f;
#pragma unroll
    for (int t = 0; t < 4; t++) {
#pragma unroll
        for (int rg = 0; rg < 4; rg++) {
            int en = ent[t * 16 + qd * 4 + rg];
            if (en < 0) continue;
            float g = gates[en];
            atomicAdd(&x1[(size_t)(en >> 1) * ND + d0 + col], g * (acc[t][rg] + bias));
        }
    }
}

// ---------------- Final: out = x1 (fp32 copy) ----------------
__launch_bounds__(256)
__global__ void final_kernel(const float* __restrict__ x1, float* __restrict__ out) {
    int i = blockIdx.x * 256 + threadIdx.x;
    out[i] = x1[i];
}

extern "C" void kernel_launch(void* const* d_in, const int* in_sizes, int n_in,
                              void* d_out, int out_size, void* d_ws, size_t ws_size,
                              hipStream_t stream) {
    const float* x    = (const float*)d_in[0];
    const float* wq   = (const float*)d_in[1];
    const float* wk   = (const float*)d_in[2];
    const float* wvp  = (const float*)d_in[3];
    const float* wo   = (const float*)d_in[4];
    const float* ln1g = (const float*)d_in[5];
    const float* ln1b = (const float*)d_in[6];
    const float* ln2g = (const float*)d_in[7];
    const float* ln2b = (const float*)d_in[8];
    const float* gw   = (const float*)d_in[9];
    const float* gb   = (const float*)d_in[10];
    const float* be   = (const float*)d_in[11];
    const float* w1   = (const float*)d_in[12];
    const float* b1   = (const float*)d_in[13];
    const float* w2   = (const float*)d_in[14];
    const float* b2   = (const float*)d_in[15];
    float* out = (float*)d_out;

    const size_t TDn = (size_t)NT * ND; // 3,145,728
    const size_t TGn = (size_t)NT * GW; // 1,048,576
    float* W = (float*)d_ws;
    // Workspace 40.2 MiB (identical to the verified R0 layout):
    // [routing 41216 f][x1 fp32 TDn][h fp32 TDn][R: q,k,v,og fp32 4*TGn]
    // h2 (bf16, TDn) reuses h's region; mid (bf16, 2*NT*FQ = 2*TDn) reuses R.
    int*   cnt   = (int*)W;                  // 8
    int*   list  = cnt + NE;                 // 32768
    float* gates = (float*)(list + NE * NT); // 8192 (ends 40968)
    float* x1 = W + 41216;
    float* h  = x1 + TDn;
    float* R0 = h + TDn;
    float* q  = R0;
    float* k  = R0 + TGn;
    float* v  = R0 + 2 * TGn;
    float* og = R0 + 3 * TGn;
    bf16*  h2  = (bf16*)h;   // LN2 out (bf16), overwrites LN1 h (route fuses LN2)
    bf16*  mid = (bf16*)R0;  // [2*NT][FQ] bf16 = 2*TDn bf16, fits in 4*TGn floats

    hipMemsetAsync(cnt, 0, NE * sizeof(int), stream);

    ln_kernel<<<NT, 256, 0, stream>>>(x, ln1g, ln1b, h);
    for (int g = 0; g < NG; g++) {
        qkv3<<<dim3(NT / 64, 12), 256, 0, stream>>>(h, wq, wk, wvp, g * GW, q, k, v);
        attn_kernel<<<dim3(NS / 64, HG, NB), 512, 0, stream>>>(q, k, v, og);
        // x1 (g==0: = x + og@wo_g ; else += og@wo_g). wo rows g*GW..(g+1)*GW.
        if (g == 0)
            sgemm3<1><<<dim3(NT / 64, ND / 64), 256, 0, stream>>>(
                og, GW, wo + (size_t)g * GW * ND, ND, 0, x, x1, ND, GW);
        else
            sgemm3<2><<<dim3(NT / 64, ND / 64), 256, 0, stream>>>(
                og, GW, wo + (size_t)g * GW * ND, ND, 0, nullptr, x1, ND, GW);
    }
    // route fuses LN2: writes h2 (bf16) + top-2 lists/gates (after last sgemm3,
    // which frees h). x1 is complete here.
    route_kernel<<<NT / 4, 256, 0, stream>>>(x1, ln2g, ln2b, gw, gb, be, cnt, list,
                                             gates, h2);
    for (int p = 0; p < NP; p++) {
        int fcol0 = p * FQ;
        moe_gemm1<<<dim3(NE * (NT / 64), FQ / 64), 256, 0, stream>>>(
            h2, w1, b1, cnt, list, mid, fcol0);
        moe_gemm2<<<dim3(NE * (NT / 64), ND / 64), 256, 0, stream>>>(
            mid, w2, b2, cnt, list, gates, x1, fcol0, p == 0 ? 1 : 0);
    }
    final_kernel<<<TDn / 256, 256, 0, stream>>>(x1, out);
}

// Round 7
// 1163.901 us; speedup vs baseline: 1.5740x; 1.0289x over previous
//
#include <hip/hip_runtime.h>
#include <hip/hip_bf16.h>

using bf16 = __hip_bfloat16;

constexpr int NB = 8, NS = 512, ND = 768, NH = 12, NE = 8, NF = 3072, NT = 4096;
constexpr int HG = 4;            // heads per attention group
constexpr int NG = NH / HG;      // 3 groups
constexpr int GW = HG * 64;      // 256: qkv group width
constexpr int FQ = 768;          // F columns per MoE pass
constexpr int NP = NF / FQ;      // 4 passes
constexpr int CS = 32;           // cnt stride (ints) -> 128B, one cacheline per expert

typedef __attribute__((ext_vector_type(8))) short v8s;
typedef __attribute__((ext_vector_type(4))) float v4f;

__device__ __forceinline__ short f2bf(float v) {
    bf16 t = __float2bfloat16(v);
    return *reinterpret_cast<short*>(&t);
}
__device__ __forceinline__ float bf2f(short s) {
    bf16 t = *reinterpret_cast<bf16*>(&s);
    return __bfloat162float(t);
}

// ---------------- LayerNorm (fp32 in) -> fp32 out (LN1 only) ----------------
__launch_bounds__(256)
__global__ void ln_kernel(const float* __restrict__ x, const float* __restrict__ g,
                          const float* __restrict__ b, float* __restrict__ out) {
    const int t = blockIdx.x;
    const int tid = threadIdx.x;
    const float* xr = x + (size_t)t * ND;
    float v0 = xr[tid], v1 = xr[tid + 256], v2 = xr[tid + 512];
    float s = v0 + v1 + v2;
    float ss = v0 * v0 + v1 * v1 + v2 * v2;
#pragma unroll
    for (int off = 32; off >= 1; off >>= 1) {
        s += __shfl_xor(s, off);
        ss += __shfl_xor(ss, off);
    }
    __shared__ float rs[4], rss[4];
    const int wv = tid >> 6, ln = tid & 63;
    if (ln == 0) { rs[wv] = s; rss[wv] = ss; }
    __syncthreads();
    float S = rs[0] + rs[1] + rs[2] + rs[3];
    float SS = rss[0] + rss[1] + rss[2] + rss[3];
    float mu = S * (1.0f / ND);
    float var = SS * (1.0f / ND) - mu * mu;
    float r = rsqrtf(fmaxf(var, 0.f) + 1e-5f);
    float* orow = out + (size_t)t * ND;
    orow[tid]       = (v0 - mu) * r * g[tid]       + b[tid];
    orow[tid + 256] = (v1 - mu) * r * g[tid + 256] + b[tid + 256];
    orow[tid + 512] = (v2 - mu) * r * g[tid + 512] + b[tid + 512];
}

// ============ split-bf16 (bf16x3) MFMA GEMM core: fp32-accurate ============
// a = a_hi + a_lo (bf16 each); a*b ~= ah*bh + ah*bl + al*bh (rel err ~2^-18).
// 64x64 tile, BK=32, 4 waves, verified moe_gemm fragment layout:
//   A[m=lane&15][k=quad*8+j], B stored [n][k], D row=quad*4+reg, col=lane&15.
__device__ __forceinline__ void gemm3_core(const float* __restrict__ A, int lda,
                                           const float* __restrict__ Bsrc, int ldb,
                                           int Kd, int m0, v4f acc[4],
                                           short* Ah, short* Al, short* Bh, short* Bl) {
    const int tid = threadIdx.x, lane = tid & 63, wv = tid >> 6;
    const int qd = lane >> 4, l16 = lane & 15;
    const int ar = tid >> 2, ac = (tid & 3) * 8;   // A staging: row, k-offset
    const int bn = tid & 63, bk = (tid >> 6) * 8;  // B staging: n, k-offset
    const float* Arow = A + (size_t)(m0 + ar) * lda;
    for (int k0 = 0; k0 < Kd; k0 += 32) {
        {
            const float* asrc = Arow + k0 + ac;
            v8s ah, al;
#pragma unroll
            for (int j = 0; j < 8; j++) {
                float vv = asrc[j];
                short hi = f2bf(vv);
                ah[j] = hi;
                al[j] = f2bf(vv - bf2f(hi));
            }
            *(v8s*)&Ah[ar * 40 + ac] = ah;
            *(v8s*)&Al[ar * 40 + ac] = al;
        }
        {
            const float* bsrc = Bsrc + (size_t)(k0 + bk) * ldb + bn;
            v8s bh_, bl_;
#pragma unroll
            for (int j = 0; j < 8; j++) {
                float vv = bsrc[(size_t)j * ldb];
                short hi = f2bf(vv);
                bh_[j] = hi;
                bl_[j] = f2bf(vv - bf2f(hi));
            }
            *(v8s*)&Bh[bn * 40 + bk] = bh_;
            *(v8s*)&Bl[bn * 40 + bk] = bl_;
        }
        __syncthreads();
        v8s bhf = *(const v8s*)&Bh[(wv * 16 + l16) * 40 + qd * 8];
        v8s blf = *(const v8s*)&Bl[(wv * 16 + l16) * 40 + qd * 8];
#pragma unroll
        for (int t = 0; t < 4; t++) {
            v8s ahf = *(const v8s*)&Ah[(t * 16 + l16) * 40 + qd * 8];
            v8s alf = *(const v8s*)&Al[(t * 16 + l16) * 40 + qd * 8];
            acc[t] = __builtin_amdgcn_mfma_f32_16x16x32_bf16(ahf, bhf, acc[t], 0, 0, 0);
            acc[t] = __builtin_amdgcn_mfma_f32_16x16x32_bf16(ahf, blf, acc[t], 0, 0, 0);
            acc[t] = __builtin_amdgcn_mfma_f32_16x16x32_bf16(alf, bhf, acc[t], 0, 0, 0);
        }
        __syncthreads();
    }
}

// ---- generic split-bf16 GEMM. RES_MODE: 0 store, 1 store Res+acc, 2 C += acc ----
template <int RES_MODE>
__launch_bounds__(256)
__global__ void sgemm3(const float* __restrict__ A, int lda, const float* __restrict__ Bw,
                       int ldb, int bcol0, const float* __restrict__ Res,
                       float* __restrict__ C, int ldc, int Kd) {
    __shared__ short Ah[64 * 40], Al[64 * 40], Bh[64 * 40], Bl[64 * 40];
    const int m0 = blockIdx.x * 64, n0 = blockIdx.y * 64;
    v4f acc[4] = {};
    gemm3_core(A, lda, Bw + bcol0 + n0, ldb, Kd, m0, acc, Ah, Al, Bh, Bl);
    const int tid = threadIdx.x, lane = tid & 63, wv = tid >> 6;
    const int qd = lane >> 4, l16 = lane & 15;
    const int c = n0 + wv * 16 + l16;
#pragma unroll
    for (int t = 0; t < 4; t++)
#pragma unroll
        for (int rg = 0; rg < 4; rg++) {
            const int r = m0 + t * 16 + qd * 4 + rg;
            size_t ci = (size_t)r * ldc + c;
            if (RES_MODE == 0) C[ci] = acc[t][rg];
            else if (RES_MODE == 1) C[ci] = Res[ci] + acc[t][rg];
            else C[ci] += acc[t][rg];
        }
}

// ---- merged Q/K/V projection for one head-group (grid 64 x 12, 3 blocks/CU) ----
__launch_bounds__(256)
__global__ void qkv3(const float* __restrict__ h, const float* __restrict__ wq,
                     const float* __restrict__ wk, const float* __restrict__ wv,
                     int bcol0, float* __restrict__ qo, float* __restrict__ ko,
                     float* __restrict__ vo) {
    __shared__ short Ah[64 * 40], Al[64 * 40], Bh[64 * 40], Bl[64 * 40];
    const int m0 = blockIdx.x * 64;
    const int ysel = blockIdx.y >> 2, ny = blockIdx.y & 3;
    const int n0 = ny * 64;
    const float* Bw = (ysel == 0) ? wq : (ysel == 1) ? wk : wv;
    float* C = (ysel == 0) ? qo : (ysel == 1) ? ko : vo;
    v4f acc[4] = {};
    gemm3_core(h, ND, Bw + bcol0 + n0, ND, ND, m0, acc, Ah, Al, Bh, Bl);
    const int tid = threadIdx.x, lane = tid & 63, wv_ = tid >> 6;
    const int qd = lane >> 4, l16 = lane & 15;
    const int c = n0 + wv_ * 16 + l16;
#pragma unroll
    for (int t = 0; t < 4; t++)
#pragma unroll
        for (int rg = 0; rg < 4; rg++) {
            const int r = m0 + t * 16 + qd * 4 + rg;
            C[(size_t)r * GW + c] = acc[t][rg];
        }
}

// ------- fp32 flash attention: 32-row q-tiles, 512 threads, 2 blocks/CU -------
// Thread owns 1 q-row x 4 cols. Per-element FMA/softmax order bit-identical to
// the verified version (same d0/dd order, same 16-lane shfl groups); only the
// thread->work mapping and grid changed (2x blocks for latency hiding).
__launch_bounds__(512)
__global__ void attn_kernel(const float* __restrict__ q, const float* __restrict__ k,
                            const float* __restrict__ v, float* __restrict__ o) {
    __shared__ float qs[32][68];
    __shared__ float kp[64][68]; // K tile; rows 0..31 reused as P tile
    __shared__ float vs[64][68];
    const int qt = blockIdx.x, hl = blockIdx.y, b = blockIdx.z;
    const int tid = threadIdx.x;
    const int tx = tid & 15, rw = tid >> 4;  // rw 0..31
    const int hc = hl * 64;
    {
        const v4f* q4 = (const v4f*)(q + ((size_t)b * NS + qt * 32) * GW + hc);
        *(v4f*)&qs[rw][tx * 4] = q4[(size_t)rw * (GW / 4) + tx];
    }
    float oa[4] = {};
    float mi = -1.0e30f, li = 0.f;
    for (int kt = 0; kt < NS / 64; kt++) {
        __syncthreads();
        {
            const v4f* k4 = (const v4f*)(k + ((size_t)b * NS + kt * 64) * GW + hc);
            const v4f* v4 = (const v4f*)(v + ((size_t)b * NS + kt * 64) * GW + hc);
#pragma unroll
            for (int i = 0; i < 2; i++) {
                int idx = tid + 512 * i;
                int r = idx >> 4, c4 = idx & 15;
                *(v4f*)&kp[r][c4 * 4] = k4[(size_t)r * (GW / 4) + c4];
                *(v4f*)&vs[r][c4 * 4] = v4[(size_t)r * (GW / 4) + c4];
            }
        }
        __syncthreads();
        float s[4] = {};
#pragma unroll
        for (int d0 = 0; d0 < 64; d0 += 4) {
            v4f av = *(const v4f*)&qs[rw][d0];
            v4f bv[4];
#pragma unroll
            for (int j = 0; j < 4; j++) bv[j] = *(const v4f*)&kp[tx + 16 * j][d0];
#pragma unroll
            for (int dd = 0; dd < 4; dd++)
#pragma unroll
                for (int j = 0; j < 4; j++) s[j] += av[dd] * bv[j][dd];
        }
#pragma unroll
        for (int j = 0; j < 4; j++) s[j] *= 0.125f; // 1/sqrt(DH=64)
        float mt = fmaxf(fmaxf(s[0], s[1]), fmaxf(s[2], s[3]));
#pragma unroll
        for (int off = 1; off < 16; off <<= 1) mt = fmaxf(mt, __shfl_xor(mt, off));
        float mn = fmaxf(mi, mt);
        float al = __expf(mi - mn);
        mi = mn;
        float rsum = 0.f;
#pragma unroll
        for (int j = 0; j < 4; j++) {
            s[j] = __expf(s[j] - mn);
            rsum += s[j];
        }
#pragma unroll
        for (int off = 1; off < 16; off <<= 1) rsum += __shfl_xor(rsum, off);
        li = li * al + rsum;
        __syncthreads(); // reads of kp-as-K done
#pragma unroll
        for (int j = 0; j < 4; j++) {
            kp[rw][tx + 16 * j] = s[j];
            oa[j] *= al;
        }
        __syncthreads(); // P visible
#pragma unroll
        for (int d0 = 0; d0 < 64; d0 += 4) {
            v4f av = *(const v4f*)&kp[rw][d0];
#pragma unroll
            for (int dd = 0; dd < 4; dd++) {
                float bb[4];
#pragma unroll
                for (int j = 0; j < 4; j++) bb[j] = vs[d0 + dd][tx + 16 * j];
#pragma unroll
                for (int j = 0; j < 4; j++) oa[j] += av[dd] * bb[j];
            }
        }
    }
    float inv = 1.0f / li;
#pragma unroll
    for (int j = 0; j < 4; j++)
        o[((size_t)b * NS + qt * 32 + rw) * GW + hc + tx + 16 * j] = oa[j] * inv;
}

// ------- Routing + fused LN2. Padded counters (one cacheline per expert) +
// block-aggregated list reservation: <=8 global atomics per block, spread
// across 8 cachelines (was: 16384 RMWs on ONE cacheline = ~100us serial). -------
__launch_bounds__(256)
__global__ void route_kernel(const float* __restrict__ x1, const float* __restrict__ lg,
                             const float* __restrict__ lb, const float* __restrict__ gw,
                             const float* __restrict__ gb, const float* __restrict__ be,
                             int* __restrict__ cnt, int* __restrict__ list,
                             float* __restrict__ gates, bf16* __restrict__ h2) {
    __shared__ int se[8], sent[8];
    const int lane = threadIdx.x & 63;
    const int wv = threadIdx.x >> 6;
    const int t = blockIdx.x * 4 + wv;   // grid is exactly NT/4
    const float* xr = x1 + (size_t)t * ND;
    float xv[12];
    float s = 0.f, ss = 0.f;
#pragma unroll
    for (int i = 0; i < 12; i++) {
        xv[i] = xr[i * 64 + lane];
        s += xv[i];
        ss += xv[i] * xv[i];
    }
#pragma unroll
    for (int off = 32; off >= 1; off >>= 1) {
        s += __shfl_xor(s, off);
        ss += __shfl_xor(ss, off);
    }
    float mu = s * (1.0f / ND);
    float var = ss * (1.0f / ND) - mu * mu;
    float r = rsqrtf(fmaxf(var, 0.f) + 1e-5f);
    float le[NE];
#pragma unroll
    for (int e = 0; e < NE; e++) le[e] = 0.f;
    bf16* h2r = h2 + (size_t)t * ND;
#pragma unroll
    for (int i = 0; i < 12; i++) {
        int d = i * 64 + lane;
        float hn = (xv[i] - mu) * r * lg[d] + lb[d];
        h2r[d] = __float2bfloat16(hn);   // fused LN2 output
#pragma unroll
        for (int e = 0; e < NE; e++) le[e] += hn * gw[d * NE + e];
    }
#pragma unroll
    for (int off = 1; off < 64; off <<= 1)
#pragma unroll
        for (int e = 0; e < NE; e++) le[e] += __shfl_xor(le[e], off);
    // register-only top-2 over sel = le + gb + be (gates use le + gb only)
    float m1 = -1.0e30f, m2 = -1.0e30f, l1 = 0.f, l2 = 0.f;
    int i1 = 0, i2 = 0;
#pragma unroll
    for (int e = 0; e < NE; e++) {
        float lv = le[e] + gb[e];   // TAU = 1
        float sv = lv + be[e];
        bool g1 = sv > m1;
        float pm1 = m1, pl1 = l1; int pi1 = i1;
        m1 = g1 ? sv : m1; l1 = g1 ? lv : l1; i1 = g1 ? e : i1;
        bool g2 = (!g1) && (sv > m2);
        m2 = g1 ? pm1 : (g2 ? sv : m2);
        l2 = g1 ? pl1 : (g2 ? lv : l2);
        i2 = g1 ? pi1 : (g2 ? e : i2);
    }
    float m = fmaxf(l1, l2);
    float e1 = __expf(l1 - m), e2 = __expf(l2 - m);
    float inv = 1.0f / (e1 + e2);
    if (lane == 0) {
        gates[t * 2 + 0] = e1 * inv;
        gates[t * 2 + 1] = e2 * inv;
        se[wv * 2]       = i1; sent[wv * 2]       = t * 2;
        se[wv * 2 + 1]   = i2; sent[wv * 2 + 1]   = t * 2 + 1;
    }
    __syncthreads();
    if (threadIdx.x < NE) {
        const int e = threadIdx.x;
        int c = 0;
#pragma unroll
        for (int sl = 0; sl < 8; sl++) c += (se[sl] == e) ? 1 : 0;
        if (c) {
            int p = atomicAdd(&cnt[e * CS], c);
#pragma unroll
            for (int sl = 0; sl < 8; sl++)
                if (se[sl] == e) {
                    if (p < NT) list[e * NT + p] = sent[sl];
                    p++;
                }
        }
    }
}

// ==================== MFMA MoE GEMMs (verified; cnt stride CS) ====================
__launch_bounds__(256)
__global__ void moe_gemm1(const bf16* __restrict__ h2, const float* __restrict__ w1,
                          const float* __restrict__ b1, const int* __restrict__ cnt,
                          const int* __restrict__ list, bf16* __restrict__ mid, int fcol0) {
    const int e = blockIdx.x >> 6, tile = blockIdx.x & 63;
    const int n = min(cnt[e * CS], NT);
    const int r0 = tile * 64;
    if (r0 >= n) return;
    const int f0 = blockIdx.y * 64;
    __shared__ int ent[64];
    __shared__ short As[64 * 40];
    __shared__ short Bs[64 * 40];
    const int tid = threadIdx.x;
    const int lane = tid & 63, wv = tid >> 6;
    const int qd = lane >> 4, l16 = lane & 15;
    if (tid < 64) {
        int en = (r0 + tid < n) ? list[e * NT + r0 + tid] : -1;
        if (en < 0 || en >= 2 * NT) en = -1;
        ent[tid] = en;
    }
    __syncthreads();
    v4f acc[4] = {};
    const float* w1e = w1 + (size_t)e * ND * NF + fcol0 + f0;
    const int ar = tid >> 2, ac = (tid & 3) * 8;
    const int bn = tid & 63, bk = (tid >> 6) * 8;
    const int aen = ent[ar];
    for (int k0 = 0; k0 < ND; k0 += 32) {
        v8s av = {};
        if (aen >= 0)
            av = *(const v8s*)((const short*)h2 + (size_t)(aen >> 1) * ND + k0 + ac);
        *(v8s*)&As[ar * 40 + ac] = av;
        {
            const float* src = w1e + (size_t)(k0 + bk) * NF + bn;
            v8s bv;
#pragma unroll
            for (int j = 0; j < 8; j++) bv[j] = f2bf(src[(size_t)j * NF]);
            *(v8s*)&Bs[bn * 40 + bk] = bv;
        }
        __syncthreads();
        v8s bfrag = *(const v8s*)&Bs[(wv * 16 + l16) * 40 + qd * 8];
#pragma unroll
        for (int t = 0; t < 4; t++) {
            v8s afrag = *(const v8s*)&As[(t * 16 + l16) * 40 + qd * 8];
            acc[t] = __builtin_amdgcn_mfma_f32_16x16x32_bf16(afrag, bfrag, acc[t], 0, 0, 0);
        }
        __syncthreads();
    }
    const int col = wv * 16 + l16;
    const float bias = b1[e * NF + fcol0 + f0 + col];
#pragma unroll
    for (int t = 0; t < 4; t++) {
#pragma unroll
        for (int rg = 0; rg < 4; rg++) {
            int en = ent[t * 16 + qd * 4 + rg];
            if (en < 0) continue;
            float xv = acc[t][rg] + bias;
            float th = tanhf(0.7978845608028654f * (xv + 0.044715f * xv * xv * xv));
            mid[((size_t)((en & 1) * NT) + (en >> 1)) * FQ + f0 + col] =
                __float2bfloat16(0.5f * xv * (1.0f + th));
        }
    }
}

__launch_bounds__(256)
__global__ void moe_gemm2(const bf16* __restrict__ mid, const float* __restrict__ w2,
                          const float* __restrict__ b2, const int* __restrict__ cnt,
                          const int* __restrict__ list, const float* __restrict__ gates,
                          float* __restrict__ x1, int fcol0, int add_b2) {
    const int e = blockIdx.x >> 6, tile = blockIdx.x & 63;
    const int n = min(cnt[e * CS], NT);
    const int r0 = tile * 64;
    if (r0 >= n) return;
    const int d0 = blockIdx.y * 64;
    __shared__ int ent[64];
    __shared__ short As[64 * 40];
    __shared__ short Bs[64 * 40];
    const int tid = threadIdx.x;
    const int lane = tid & 63, wv = tid >> 6;
    const int qd = lane >> 4, l16 = lane & 15;
    if (tid < 64) {
        int en = (r0 + tid < n) ? list[e * NT + r0 + tid] : -1;
        if (en < 0 || en >= 2 * NT) en = -1;
        ent[tid] = en;
    }
    __syncthreads();
    v4f acc[4] = {};
    const float* w2e = w2 + (size_t)e * NF * ND + d0;
    const int ar = tid >> 2, ac = (tid & 3) * 8;
    const int bn = tid & 63, bk = (tid >> 6) * 8;
    const int aen = ent[ar];
    for (int k0 = 0; k0 < FQ; k0 += 32) {
        v8s av = {};
        if (aen >= 0)
            av = *(const v8s*)((const short*)mid +
                               ((size_t)((aen & 1) * NT) + (aen >> 1)) * FQ + k0 + ac);
        *(v8s*)&As[ar * 40 + ac] = av;
        {
            const float* src = w2e + (size_t)(fcol0 + k0 + bk) * ND + bn;
            v8s bv;
#pragma unroll
            for (int j = 0; j < 8; j++) bv[j] = f2bf(src[(size_t)j * ND]);
            *(v8s*)&Bs[bn * 40 + bk] = bv;
        }
        __syncthreads();
        v8s bfrag = *(const v8s*)&Bs[(wv * 16 + l16) * 40 + qd * 8];
#pragma unroll
        for (int t = 0; t < 4; t++) {
            v8s afrag = *(const v8s*)&As[(t * 16 + l16) * 40 + qd * 8];
            acc[t] = __builtin_amdgcn_mfma_f32_16x16x32_bf16(afrag, bfrag, acc[t], 0, 0, 0);
        }
        __syncthreads();
    }
    const int col = wv * 16 + l16;
    const float bias = add_b2 ? b2[e * ND + d0 + col] : 0.f;
#pragma unroll
    for (int t = 0; t < 4; t++) {
#pragma unroll
        for (int rg = 0; rg < 4; rg++) {
            int en = ent[t * 16 + qd * 4 + rg];
            if (en < 0) continue;
            float g = gates[en];
            atomicAdd(&x1[(size_t)(en >> 1) * ND + d0 + col], g * (acc[t][rg] + bias));
        }
    }
}

// ---------------- Final: out = x1 (fp32 copy) ----------------
__launch_bounds__(256)
__global__ void final_kernel(const float* __restrict__ x1, float* __restrict__ out) {
    int i = blockIdx.x * 256 + threadIdx.x;
    out[i] = x1[i];
}

extern "C" void kernel_launch(void* const* d_in, const int* in_sizes, int n_in,
                              void* d_out, int out_size, void* d_ws, size_t ws_size,
                              hipStream_t stream) {
    const float* x    = (const float*)d_in[0];
    const float* wq   = (const float*)d_in[1];
    const float* wk   = (const float*)d_in[2];
    const float* wvp  = (const float*)d_in[3];
    const float* wo   = (const float*)d_in[4];
    const float* ln1g = (const float*)d_in[5];
    const float* ln1b = (const float*)d_in[6];
    const float* ln2g = (const float*)d_in[7];
    const float* ln2b = (const float*)d_in[8];
    const float* gw   = (const float*)d_in[9];
    const float* gb   = (const float*)d_in[10];
    const float* be   = (const float*)d_in[11];
    const float* w1   = (const float*)d_in[12];
    const float* b1   = (const float*)d_in[13];
    const float* w2   = (const float*)d_in[14];
    const float* b2   = (const float*)d_in[15];
    float* out = (float*)d_out;

    const size_t TDn = (size_t)NT * ND; // 3,145,728
    const size_t TGn = (size_t)NT * GW; // 1,048,576
    float* W = (float*)d_ws;
    // Workspace 40.2 MiB (verified layout):
    // [cnt 256][list 32768][gates 8192] = 41216 f, then x1, h, R.
    int*   cnt   = (int*)W;                       // 256 ints (8 x 128B lines)
    int*   list  = cnt + NE * CS;                 // 32768
    float* gates = (float*)(list + NE * NT);      // 8192 (ends 41216)
    float* x1 = W + 41216;
    float* h  = x1 + TDn;
    float* R0 = h + TDn;
    float* q  = R0;
    float* k  = R0 + TGn;
    float* v  = R0 + 2 * TGn;
    float* og = R0 + 3 * TGn;
    bf16*  h2  = (bf16*)h;   // LN2 out (bf16), overwrites LN1 h (route fuses LN2)
    bf16*  mid = (bf16*)R0;  // [2*NT][FQ] bf16 = 2*TDn bf16, fits in 4*TGn floats

    hipMemsetAsync(cnt, 0, NE * CS * sizeof(int), stream);

    ln_kernel<<<NT, 256, 0, stream>>>(x, ln1g, ln1b, h);
    for (int g = 0; g < NG; g++) {
        qkv3<<<dim3(NT / 64, 12), 256, 0, stream>>>(h, wq, wk, wvp, g * GW, q, k, v);
        attn_kernel<<<dim3(NS / 32, HG, NB), 512, 0, stream>>>(q, k, v, og);
        // x1 (g==0: = x + og@wo_g ; else += og@wo_g). wo rows g*GW..(g+1)*GW.
        if (g == 0)
            sgemm3<1><<<dim3(NT / 64, ND / 64), 256, 0, stream>>>(
                og, GW, wo + (size_t)g * GW * ND, ND, 0, x, x1, ND, GW);
        else
            sgemm3<2><<<dim3(NT / 64, ND / 64), 256, 0, stream>>>(
                og, GW, wo + (size_t)g * GW * ND, ND, 0, nullptr, x1, ND, GW);
    }
    // route fuses LN2: writes h2 (bf16) + top-2 lists/gates.
    route_kernel<<<NT / 4, 256, 0, stream>>>(x1, ln2g, ln2b, gw, gb, be, cnt, list,
                                             gates, h2);
    for (int p = 0; p < NP; p++) {
        int fcol0 = p * FQ;
        moe_gemm1<<<dim3(NE * (NT / 64), FQ / 64), 256, 0, stream>>>(
            h2, w1, b1, cnt, list, mid, fcol0);
        moe_gemm2<<<dim3(NE * (NT / 64), ND / 64), 256, 0, stream>>>(
            mid, w2, b2, cnt, list, gates, x1, fcol0, p == 0 ? 1 : 0);
    }
    final_kernel<<<TDn / 256, 256, 0, stream>>>(x1, out);
}

// Round 8
// 1162.583 us; speedup vs baseline: 1.5758x; 1.0011x over previous
//
#include <hip/hip_runtime.h>
#include <hip/hip_bf16.h>

using bf16 = __hip_bfloat16;

constexpr int NB = 8, NS = 512, ND = 768, NH = 12, NE = 8, NF = 3072, NT = 4096;
constexpr int HG = 4;            // heads per attention group
constexpr int NG = NH / HG;      // 3 groups
constexpr int GW = HG * 64;      // 256: qkv group width
constexpr int FQ = 768;          // F columns per MoE pass
constexpr int NP = NF / FQ;      // 4 passes
constexpr int CS = 32;           // cnt stride (ints) -> 128B, one cacheline per expert

typedef __attribute__((ext_vector_type(8))) short v8s;
typedef __attribute__((ext_vector_type(4))) float v4f;

__device__ __forceinline__ short f2bf(float v) {
    bf16 t = __float2bfloat16(v);
    return *reinterpret_cast<short*>(&t);
}
__device__ __forceinline__ float bf2f(short s) {
    bf16 t = *reinterpret_cast<bf16*>(&s);
    return __bfloat162float(t);
}

// ---------------- LayerNorm (fp32 in) -> fp32 out (LN1 only) ----------------
__launch_bounds__(256)
__global__ void ln_kernel(const float* __restrict__ x, const float* __restrict__ g,
                          const float* __restrict__ b, float* __restrict__ out) {
    const int t = blockIdx.x;
    const int tid = threadIdx.x;
    const float* xr = x + (size_t)t * ND;
    float v0 = xr[tid], v1 = xr[tid + 256], v2 = xr[tid + 512];
    float s = v0 + v1 + v2;
    float ss = v0 * v0 + v1 * v1 + v2 * v2;
#pragma unroll
    for (int off = 32; off >= 1; off >>= 1) {
        s += __shfl_xor(s, off);
        ss += __shfl_xor(ss, off);
    }
    __shared__ float rs[4], rss[4];
    const int wv = tid >> 6, ln = tid & 63;
    if (ln == 0) { rs[wv] = s; rss[wv] = ss; }
    __syncthreads();
    float S = rs[0] + rs[1] + rs[2] + rs[3];
    float SS = rss[0] + rss[1] + rss[2] + rss[3];
    float mu = S * (1.0f / ND);
    float var = SS * (1.0f / ND) - mu * mu;
    float r = rsqrtf(fmaxf(var, 0.f) + 1e-5f);
    float* orow = out + (size_t)t * ND;
    orow[tid]       = (v0 - mu) * r * g[tid]       + b[tid];
    orow[tid + 256] = (v1 - mu) * r * g[tid + 256] + b[tid + 256];
    orow[tid + 512] = (v2 - mu) * r * g[tid + 512] + b[tid + 512];
}

// ============ split-bf16 (bf16x3) MFMA GEMM core: fp32-accurate ============
__device__ __forceinline__ void gemm3_core(const float* __restrict__ A, int lda,
                                           const float* __restrict__ Bsrc, int ldb,
                                           int Kd, int m0, v4f acc[4],
                                           short* Ah, short* Al, short* Bh, short* Bl) {
    const int tid = threadIdx.x, lane = tid & 63, wv = tid >> 6;
    const int qd = lane >> 4, l16 = lane & 15;
    const int ar = tid >> 2, ac = (tid & 3) * 8;   // A staging: row, k-offset
    const int bn = tid & 63, bk = (tid >> 6) * 8;  // B staging: n, k-offset
    const float* Arow = A + (size_t)(m0 + ar) * lda;
    for (int k0 = 0; k0 < Kd; k0 += 32) {
        {
            const float* asrc = Arow + k0 + ac;
            v8s ah, al;
#pragma unroll
            for (int j = 0; j < 8; j++) {
                float vv = asrc[j];
                short hi = f2bf(vv);
                ah[j] = hi;
                al[j] = f2bf(vv - bf2f(hi));
            }
            *(v8s*)&Ah[ar * 40 + ac] = ah;
            *(v8s*)&Al[ar * 40 + ac] = al;
        }
        {
            const float* bsrc = Bsrc + (size_t)(k0 + bk) * ldb + bn;
            v8s bh_, bl_;
#pragma unroll
            for (int j = 0; j < 8; j++) {
                float vv = bsrc[(size_t)j * ldb];
                short hi = f2bf(vv);
                bh_[j] = hi;
                bl_[j] = f2bf(vv - bf2f(hi));
            }
            *(v8s*)&Bh[bn * 40 + bk] = bh_;
            *(v8s*)&Bl[bn * 40 + bk] = bl_;
        }
        __syncthreads();
        v8s bhf = *(const v8s*)&Bh[(wv * 16 + l16) * 40 + qd * 8];
        v8s blf = *(const v8s*)&Bl[(wv * 16 + l16) * 40 + qd * 8];
#pragma unroll
        for (int t = 0; t < 4; t++) {
            v8s ahf = *(const v8s*)&Ah[(t * 16 + l16) * 40 + qd * 8];
            v8s alf = *(const v8s*)&Al[(t * 16 + l16) * 40 + qd * 8];
            acc[t] = __builtin_amdgcn_mfma_f32_16x16x32_bf16(ahf, bhf, acc[t], 0, 0, 0);
            acc[t] = __builtin_amdgcn_mfma_f32_16x16x32_bf16(ahf, blf, acc[t], 0, 0, 0);
            acc[t] = __builtin_amdgcn_mfma_f32_16x16x32_bf16(alf, bhf, acc[t], 0, 0, 0);
        }
        __syncthreads();
    }
}

// ---- generic split-bf16 GEMM. RES_MODE: 0 store, 1 store Res+acc, 2 C += acc ----
template <int RES_MODE>
__launch_bounds__(256)
__global__ void sgemm3(const float* __restrict__ A, int lda, const float* __restrict__ Bw,
                       int ldb, int bcol0, const float* __restrict__ Res,
                       float* __restrict__ C, int ldc, int Kd) {
    __shared__ short Ah[64 * 40], Al[64 * 40], Bh[64 * 40], Bl[64 * 40];
    const int m0 = blockIdx.x * 64, n0 = blockIdx.y * 64;
    v4f acc[4] = {};
    gemm3_core(A, lda, Bw + bcol0 + n0, ldb, Kd, m0, acc, Ah, Al, Bh, Bl);
    const int tid = threadIdx.x, lane = tid & 63, wv = tid >> 6;
    const int qd = lane >> 4, l16 = lane & 15;
    const int c = n0 + wv * 16 + l16;
#pragma unroll
    for (int t = 0; t < 4; t++)
#pragma unroll
        for (int rg = 0; rg < 4; rg++) {
            const int r = m0 + t * 16 + qd * 4 + rg;
            size_t ci = (size_t)r * ldc + c;
            if (RES_MODE == 0) C[ci] = acc[t][rg];
            else if (RES_MODE == 1) C[ci] = Res[ci] + acc[t][rg];
            else C[ci] += acc[t][rg];
        }
}

// ---- merged Q/K/V projection for one head-group (grid 64 x 12, 3 blocks/CU) ----
__launch_bounds__(256)
__global__ void qkv3(const float* __restrict__ h, const float* __restrict__ wq,
                     const float* __restrict__ wk, const float* __restrict__ wv,
                     int bcol0, float* __restrict__ qo, float* __restrict__ ko,
                     float* __restrict__ vo) {
    __shared__ short Ah[64 * 40], Al[64 * 40], Bh[64 * 40], Bl[64 * 40];
    const int m0 = blockIdx.x * 64;
    const int ysel = blockIdx.y >> 2, ny = blockIdx.y & 3;
    const int n0 = ny * 64;
    const float* Bw = (ysel == 0) ? wq : (ysel == 1) ? wk : wv;
    float* C = (ysel == 0) ? qo : (ysel == 1) ? ko : vo;
    v4f acc[4] = {};
    gemm3_core(h, ND, Bw + bcol0 + n0, ND, ND, m0, acc, Ah, Al, Bh, Bl);
    const int tid = threadIdx.x, lane = tid & 63, wv_ = tid >> 6;
    const int qd = lane >> 4, l16 = lane & 15;
    const int c = n0 + wv_ * 16 + l16;
#pragma unroll
    for (int t = 0; t < 4; t++)
#pragma unroll
        for (int rg = 0; rg < 4; rg++) {
            const int r = m0 + t * 16 + qd * 4 + rg;
            C[(size_t)r * GW + c] = acc[t][rg];
        }
}

// ------- fp32 flash attention: 32-row q-tiles, 512 threads, 2 blocks/CU -------
__launch_bounds__(512)
__global__ void attn_kernel(const float* __restrict__ q, const float* __restrict__ k,
                            const float* __restrict__ v, float* __restrict__ o) {
    __shared__ float qs[32][68];
    __shared__ float kp[64][68]; // K tile; rows 0..31 reused as P tile
    __shared__ float vs[64][68];
    const int qt = blockIdx.x, hl = blockIdx.y, b = blockIdx.z;
    const int tid = threadIdx.x;
    const int tx = tid & 15, rw = tid >> 4;  // rw 0..31
    const int hc = hl * 64;
    {
        const v4f* q4 = (const v4f*)(q + ((size_t)b * NS + qt * 32) * GW + hc);
        *(v4f*)&qs[rw][tx * 4] = q4[(size_t)rw * (GW / 4) + tx];
    }
    float oa[4] = {};
    float mi = -1.0e30f, li = 0.f;
    for (int kt = 0; kt < NS / 64; kt++) {
        __syncthreads();
        {
            const v4f* k4 = (const v4f*)(k + ((size_t)b * NS + kt * 64) * GW + hc);
            const v4f* v4 = (const v4f*)(v + ((size_t)b * NS + kt * 64) * GW + hc);
#pragma unroll
            for (int i = 0; i < 2; i++) {
                int idx = tid + 512 * i;
                int r = idx >> 4, c4 = idx & 15;
                *(v4f*)&kp[r][c4 * 4] = k4[(size_t)r * (GW / 4) + c4];
                *(v4f*)&vs[r][c4 * 4] = v4[(size_t)r * (GW / 4) + c4];
            }
        }
        __syncthreads();
        float s[4] = {};
#pragma unroll
        for (int d0 = 0; d0 < 64; d0 += 4) {
            v4f av = *(const v4f*)&qs[rw][d0];
            v4f bv[4];
#pragma unroll
            for (int j = 0; j < 4; j++) bv[j] = *(const v4f*)&kp[tx + 16 * j][d0];
#pragma unroll
            for (int dd = 0; dd < 4; dd++)
#pragma unroll
                for (int j = 0; j < 4; j++) s[j] += av[dd] * bv[j][dd];
        }
#pragma unroll
        for (int j = 0; j < 4; j++) s[j] *= 0.125f; // 1/sqrt(DH=64)
        float mt = fmaxf(fmaxf(s[0], s[1]), fmaxf(s[2], s[3]));
#pragma unroll
        for (int off = 1; off < 16; off <<= 1) mt = fmaxf(mt, __shfl_xor(mt, off));
        float mn = fmaxf(mi, mt);
        float al = __expf(mi - mn);
        mi = mn;
        float rsum = 0.f;
#pragma unroll
        for (int j = 0; j < 4; j++) {
            s[j] = __expf(s[j] - mn);
            rsum += s[j];
        }
#pragma unroll
        for (int off = 1; off < 16; off <<= 1) rsum += __shfl_xor(rsum, off);
        li = li * al + rsum;
        __syncthreads(); // reads of kp-as-K done
#pragma unroll
        for (int j = 0; j < 4; j++) {
            kp[rw][tx + 16 * j] = s[j];
            oa[j] *= al;
        }
        __syncthreads(); // P visible
#pragma unroll
        for (int d0 = 0; d0 < 64; d0 += 4) {
            v4f av = *(const v4f*)&kp[rw][d0];
#pragma unroll
            for (int dd = 0; dd < 4; dd++) {
                float bb[4];
#pragma unroll
                for (int j = 0; j < 4; j++) bb[j] = vs[d0 + dd][tx + 16 * j];
#pragma unroll
                for (int j = 0; j < 4; j++) oa[j] += av[dd] * bb[j];
            }
        }
    }
    float inv = 1.0f / li;
#pragma unroll
    for (int j = 0; j < 4; j++)
        o[((size_t)b * NS + qt * 32 + rw) * GW + hc + tx + 16 * j] = oa[j] * inv;
}

// ------- Routing + fused LN2; padded counters + block-aggregated atomics -------
__launch_bounds__(256)
__global__ void route_kernel(const float* __restrict__ x1, const float* __restrict__ lg,
                             const float* __restrict__ lb, const float* __restrict__ gw,
                             const float* __restrict__ gb, const float* __restrict__ be,
                             int* __restrict__ cnt, int* __restrict__ list,
                             float* __restrict__ gates, bf16* __restrict__ h2) {
    __shared__ int se[8], sent[8];
    const int lane = threadIdx.x & 63;
    const int wv = threadIdx.x >> 6;
    const int t = blockIdx.x * 4 + wv;   // grid is exactly NT/4
    const float* xr = x1 + (size_t)t * ND;
    float xv[12];
    float s = 0.f, ss = 0.f;
#pragma unroll
    for (int i = 0; i < 12; i++) {
        xv[i] = xr[i * 64 + lane];
        s += xv[i];
        ss += xv[i] * xv[i];
    }
#pragma unroll
    for (int off = 32; off >= 1; off >>= 1) {
        s += __shfl_xor(s, off);
        ss += __shfl_xor(ss, off);
    }
    float mu = s * (1.0f / ND);
    float var = ss * (1.0f / ND) - mu * mu;
    float r = rsqrtf(fmaxf(var, 0.f) + 1e-5f);
    float le[NE];
#pragma unroll
    for (int e = 0; e < NE; e++) le[e] = 0.f;
    bf16* h2r = h2 + (size_t)t * ND;
#pragma unroll
    for (int i = 0; i < 12; i++) {
        int d = i * 64 + lane;
        float hn = (xv[i] - mu) * r * lg[d] + lb[d];
        h2r[d] = __float2bfloat16(hn);   // fused LN2 output
#pragma unroll
        for (int e = 0; e < NE; e++) le[e] += hn * gw[d * NE + e];
    }
#pragma unroll
    for (int off = 1; off < 64; off <<= 1)
#pragma unroll
        for (int e = 0; e < NE; e++) le[e] += __shfl_xor(le[e], off);
    // register-only top-2 over sel = le + gb + be (gates use le + gb only)
    float m1 = -1.0e30f, m2 = -1.0e30f, l1 = 0.f, l2 = 0.f;
    int i1 = 0, i2 = 0;
#pragma unroll
    for (int e = 0; e < NE; e++) {
        float lv = le[e] + gb[e];   // TAU = 1
        float sv = lv + be[e];
        bool g1 = sv > m1;
        float pm1 = m1, pl1 = l1; int pi1 = i1;
        m1 = g1 ? sv : m1; l1 = g1 ? lv : l1; i1 = g1 ? e : i1;
        bool g2 = (!g1) && (sv > m2);
        m2 = g1 ? pm1 : (g2 ? sv : m2);
        l2 = g1 ? pl1 : (g2 ? lv : l2);
        i2 = g1 ? pi1 : (g2 ? e : i2);
    }
    float m = fmaxf(l1, l2);
    float e1 = __expf(l1 - m), e2 = __expf(l2 - m);
    float inv = 1.0f / (e1 + e2);
    if (lane == 0) {
        gates[t * 2 + 0] = e1 * inv;
        gates[t * 2 + 1] = e2 * inv;
        se[wv * 2]       = i1; sent[wv * 2]       = t * 2;
        se[wv * 2 + 1]   = i2; sent[wv * 2 + 1]   = t * 2 + 1;
    }
    __syncthreads();
    if (threadIdx.x < NE) {
        const int e = threadIdx.x;
        int c = 0;
#pragma unroll
        for (int sl = 0; sl < 8; sl++) c += (se[sl] == e) ? 1 : 0;
        if (c) {
            int p = atomicAdd(&cnt[e * CS], c);
#pragma unroll
            for (int sl = 0; sl < 8; sl++)
                if (se[sl] == e) {
                    if (p < NT) list[e * NT + p] = sent[sl];
                    p++;
                }
        }
    }
}

// ---- transpose-convert one 768x768 expert weight slice fp32 -> bf16 [n][k] ----
// dst[e][c][r] = bf16(src[e*eStride + (rowOff+r)*rowStride + colOff + c])
__launch_bounds__(256)
__global__ void cvt_w(const float* __restrict__ src, size_t eStride, int rowStride,
                      int rowOff, int colOff, short* __restrict__ dst) {
    __shared__ float tile[64][65];
    const int bx = blockIdx.x, by = blockIdx.y, e = blockIdx.z;
    const int tid = threadIdx.x;
    {
        const int c4 = (tid & 15) * 4, r = tid >> 4; // r 0..15
        const float* sp = src + (size_t)e * eStride +
                          (size_t)(rowOff + by * 64 + r) * rowStride + colOff + bx * 64 + c4;
#pragma unroll
        for (int i = 0; i < 4; i++) {
            v4f vv = *(const v4f*)(sp + (size_t)(16 * i) * rowStride);
            tile[r + 16 * i][c4] = vv[0]; tile[r + 16 * i][c4 + 1] = vv[1];
            tile[r + 16 * i][c4 + 2] = vv[2]; tile[r + 16 * i][c4 + 3] = vv[3];
        }
    }
    __syncthreads();
    {
        const int lc = tid >> 2;           // dst row (= src col) 0..63
        const int lr0 = (tid & 3) * 16;    // src row base
        short* d = dst + ((size_t)e * 768 + bx * 64 + lc) * 768 + by * 64 + lr0;
        v8s o0, o1;
#pragma unroll
        for (int j = 0; j < 8; j++) {
            o0[j] = f2bf(tile[lr0 + j][lc]);
            o1[j] = f2bf(tile[lr0 + 8 + j][lc]);
        }
        *(v8s*)d = o0;
        *(v8s*)&d[8] = o1;
    }
}

// ==================== MFMA MoE GEMMs: B-frags direct from preconverted wt ====
// wt is bf16 [e][n(64-block via blockIdx.y)][k] -- the exact B-frag layout, so
// each lane loads its 16B fragment straight from global (L2/L3-resident);
// no B LDS staging, no per-tile fp32->bf16 conversion.
__launch_bounds__(256)
__global__ void moe_gemm1(const bf16* __restrict__ h2, const short* __restrict__ wt,
                          const float* __restrict__ b1, const int* __restrict__ cnt,
                          const int* __restrict__ list, bf16* __restrict__ mid, int fcol0) {
    const int e = blockIdx.x >> 6, tile = blockIdx.x & 63;
    const int n = min(cnt[e * CS], NT);
    const int r0 = tile * 64;
    if (r0 >= n) return;
    const int f0 = blockIdx.y * 64;
    __shared__ int ent[64];
    __shared__ short As[64 * 40];
    const int tid = threadIdx.x;
    const int lane = tid & 63, wv = tid >> 6;
    const int qd = lane >> 4, l16 = lane & 15;
    if (tid < 64) {
        int en = (r0 + tid < n) ? list[e * NT + r0 + tid] : -1;
        if (en < 0 || en >= 2 * NT) en = -1;
        ent[tid] = en;
    }
    __syncthreads();
    v4f acc[4] = {};
    const short* wfr = wt + ((size_t)e * 768 + f0 + wv * 16 + l16) * 768 + qd * 8;
    const int ar = tid >> 2, ac = (tid & 3) * 8;
    const int aen = ent[ar];
    const short* arow = (const short*)h2 + (size_t)(aen >= 0 ? (aen >> 1) : 0) * ND + ac;
    for (int k0 = 0; k0 < ND; k0 += 32) {
        v8s av = {};
        if (aen >= 0) av = *(const v8s*)(arow + k0);
        *(v8s*)&As[ar * 40 + ac] = av;
        v8s bfrag = *(const v8s*)(wfr + k0);
        __syncthreads();
#pragma unroll
        for (int t = 0; t < 4; t++) {
            v8s afrag = *(const v8s*)&As[(t * 16 + l16) * 40 + qd * 8];
            acc[t] = __builtin_amdgcn_mfma_f32_16x16x32_bf16(afrag, bfrag, acc[t], 0, 0, 0);
        }
        __syncthreads();
    }
    const int col = wv * 16 + l16;
    const float bias = b1[e * NF + fcol0 + f0 + col];
#pragma unroll
    for (int t = 0; t < 4; t++) {
#pragma unroll
        for (int rg = 0; rg < 4; rg++) {
            int en = ent[t * 16 + qd * 4 + rg];
            if (en < 0) continue;
            float xv = acc[t][rg] + bias;
            float th = tanhf(0.7978845608028654f * (xv + 0.044715f * xv * xv * xv));
            mid[((size_t)((en & 1) * NT) + (en >> 1)) * FQ + f0 + col] =
                __float2bfloat16(0.5f * xv * (1.0f + th));
        }
    }
}

__launch_bounds__(256)
__global__ void moe_gemm2(const bf16* __restrict__ mid, const short* __restrict__ wt,
                          const float* __restrict__ b2, const int* __restrict__ cnt,
                          const int* __restrict__ list, const float* __restrict__ gates,
                          float* __restrict__ x1, int fcol0, int add_b2) {
    const int e = blockIdx.x >> 6, tile = blockIdx.x & 63;
    const int n = min(cnt[e * CS], NT);
    const int r0 = tile * 64;
    if (r0 >= n) return;
    const int d0 = blockIdx.y * 64;
    __shared__ int ent[64];
    __shared__ short As[64 * 40];
    const int tid = threadIdx.x;
    const int lane = tid & 63, wv = tid >> 6;
    const int qd = lane >> 4, l16 = lane & 15;
    if (tid < 64) {
        int en = (r0 + tid < n) ? list[e * NT + r0 + tid] : -1;
        if (en < 0 || en >= 2 * NT) en = -1;
        ent[tid] = en;
    }
    __syncthreads();
    v4f acc[4] = {};
    const short* wfr = wt + ((size_t)e * 768 + d0 + wv * 16 + l16) * 768 + qd * 8;
    const int ar = tid >> 2, ac = (tid & 3) * 8;
    const int aen = ent[ar];
    const short* arow = (const short*)mid +
                        ((size_t)(aen >= 0 ? ((aen & 1) * NT + (aen >> 1)) : 0)) * FQ + ac;
    for (int k0 = 0; k0 < FQ; k0 += 32) {
        v8s av = {};
        if (aen >= 0) av = *(const v8s*)(arow + k0);
        *(v8s*)&As[ar * 40 + ac] = av;
        v8s bfrag = *(const v8s*)(wfr + k0);
        __syncthreads();
#pragma unroll
        for (int t = 0; t < 4; t++) {
            v8s afrag = *(const v8s*)&As[(t * 16 + l16) * 40 + qd * 8];
            acc[t] = __builtin_amdgcn_mfma_f32_16x16x32_bf16(afrag, bfrag, acc[t], 0, 0, 0);
        }
        __syncthreads();
    }
    const int col = wv * 16 + l16;
    const float bias = add_b2 ? b2[e * ND + d0 + col] : 0.f;
#pragma unroll
    for (int t = 0; t < 4; t++) {
#pragma unroll
        for (int rg = 0; rg < 4; rg++) {
            int en = ent[t * 16 + qd * 4 + rg];
            if (en < 0) continue;
            float g = gates[en];
            atomicAdd(&x1[(size_t)(en >> 1) * ND + d0 + col], g * (acc[t][rg] + bias));
        }
    }
}

// ---------------- Final: out = x1 (fp32 copy) ----------------
__launch_bounds__(256)
__global__ void final_kernel(const float* __restrict__ x1, float* __restrict__ out) {
    int i = blockIdx.x * 256 + threadIdx.x;
    out[i] = x1[i];
}

extern "C" void kernel_launch(void* const* d_in, const int* in_sizes, int n_in,
                              void* d_out, int out_size, void* d_ws, size_t ws_size,
                              hipStream_t stream) {
    const float* x    = (const float*)d_in[0];
    const float* wq   = (const float*)d_in[1];
    const float* wk   = (const float*)d_in[2];
    const float* wvp  = (const float*)d_in[3];
    const float* wo   = (const float*)d_in[4];
    const float* ln1g = (const float*)d_in[5];
    const float* ln1b = (const float*)d_in[6];
    const float* ln2g = (const float*)d_in[7];
    const float* ln2b = (const float*)d_in[8];
    const float* gw   = (const float*)d_in[9];
    const float* gb   = (const float*)d_in[10];
    const float* be   = (const float*)d_in[11];
    const float* w1   = (const float*)d_in[12];
    const float* b1   = (const float*)d_in[13];
    const float* w2   = (const float*)d_in[14];
    const float* b2   = (const float*)d_in[15];
    float* out = (float*)d_out;

    const size_t TDn = (size_t)NT * ND; // 3,145,728
    const size_t TGn = (size_t)NT * GW; // 1,048,576
    float* W = (float*)d_ws;
    // Workspace 40.2 MiB (same footprint as verified layout):
    // [cnt 256][list 32768][gates 8192] = 41216 f, then x1(TDn), h(TDn), R(4*TGn).
    // Attention phase: h = LN1 out, R = q,k,v,og.
    // MoE phase (all of h and R dead): h2 bf16 -> R0 (TDn/2 f),
    //   wt bf16 (8*768*768 = 2,359,296 f region) -> R0 + TDn/2,
    //   mid bf16 [2NT][FQ] -> h (exactly TDn f).
    int*   cnt   = (int*)W;                       // 256 ints (8 x 128B lines)
    int*   list  = cnt + NE * CS;                 // 32768
    float* gates = (float*)(list + NE * NT);      // 8192 (ends 41216)
    float* x1 = W + 41216;
    float* h  = x1 + TDn;
    float* R0 = h + TDn;
    float* q  = R0;
    float* k  = R0 + TGn;
    float* v  = R0 + 2 * TGn;
    float* og = R0 + 3 * TGn;
    bf16*  h2  = (bf16*)R0;                 // MoE: LN2 out (over dead q/k)
    short* wt  = (short*)(R0 + TDn / 2);    // MoE: preconverted weight slice
    bf16*  mid = (bf16*)h;                  // MoE: [2*NT][FQ] bf16 (over dead h)

    hipMemsetAsync(cnt, 0, NE * CS * sizeof(int), stream);

    ln_kernel<<<NT, 256, 0, stream>>>(x, ln1g, ln1b, h);
    for (int g = 0; g < NG; g++) {
        qkv3<<<dim3(NT / 64, 12), 256, 0, stream>>>(h, wq, wk, wvp, g * GW, q, k, v);
        attn_kernel<<<dim3(NS / 32, HG, NB), 512, 0, stream>>>(q, k, v, og);
        if (g == 0)
            sgemm3<1><<<dim3(NT / 64, ND / 64), 256, 0, stream>>>(
                og, GW, wo + (size_t)g * GW * ND, ND, 0, x, x1, ND, GW);
        else
            sgemm3<2><<<dim3(NT / 64, ND / 64), 256, 0, stream>>>(
                og, GW, wo + (size_t)g * GW * ND, ND, 0, nullptr, x1, ND, GW);
    }
    // route fuses LN2: writes h2 (bf16) + top-2 lists/gates.
    route_kernel<<<NT / 4, 256, 0, stream>>>(x1, ln2g, ln2b, gw, gb, be, cnt, list,
                                             gates, h2);
    for (int p = 0; p < NP; p++) {
        int fcol0 = p * FQ;
        // wt = bf16(w1[e][:, fcol0+f])^T -> [e][f][d]
        cvt_w<<<dim3(12, 12, NE), 256, 0, stream>>>(w1, (size_t)ND * NF, NF, 0, fcol0, wt);
        moe_gemm1<<<dim3(NE * (NT / 64), FQ / 64), 256, 0, stream>>>(
            h2, wt, b1, cnt, list, mid, fcol0);
        // wt = bf16(w2[e][fcol0+f][:])^T -> [e][d][f]
        cvt_w<<<dim3(12, 12, NE), 256, 0, stream>>>(w2, (size_t)NF * ND, ND, fcol0, 0, wt);
        moe_gemm2<<<dim3(NE * (NT / 64), ND / 64), 256, 0, stream>>>(
            mid, wt, b2, cnt, list, gates, x1, fcol0, p == 0 ? 1 : 0);
    }
    final_kernel<<<TDn / 256, 256, 0, stream>>>(x1, out);
}